// Round 6
// baseline (97.220 us; speedup 1.0000x reference)
//
#include <hip/hip_runtime.h>
#include <math.h>

#define LOG2_10 3.3219280948873623f
#define PI_F 3.14159265358979f
#define INV2PI 0.15915494309189535f
#define PW_SCALE 256.0f   // lifts Pw out of f16-subnormal range; cancels in out = num/F1

// LDS / image row strides in f16 elements
#define SP 128   // phiT / B3T: j folded 201->101, Kpad=128 (4 MFMA K-steps), 16 granules, XOR row&7
#define SA 128   // A2: 16 granules, XOR row&7
#define ST 64    // TcT: 8 granules, XOR row&7

typedef _Float16 half8 __attribute__((ext_vector_type(8)));
typedef _Float16 half4 __attribute__((ext_vector_type(4)));
typedef _Float16 half2v __attribute__((ext_vector_type(2)));
typedef float f32x4 __attribute__((ext_vector_type(4)));

__device__ __forceinline__ float fast_cos(float x_rev) {
    return __builtin_amdgcn_cosf(__builtin_amdgcn_fractf(x_rev));
}

__device__ __forceinline__ float atan2_pos(float y, float x) {
    // assumes y >= 0; returns atan2(y,x) in [0, pi]
    float ax = __builtin_fabsf(x);
    float mn = fminf(ax, y), mx = fmaxf(ax, y);
    float a = mn * __builtin_amdgcn_rcpf(mx);
    float t = a * a;
    float p = fmaf(fmaf(fmaf(fmaf(fmaf(-0.0117212f, t, 0.05265332f), t,
              -0.11643287f), t, 0.19354346f), t, -0.33262347f), t, 0.99997726f);
    p *= a;
    p = (y > ax) ? (1.57079632679f - p) : p;
    p = (x < 0.0f) ? (3.14159265359f - p) : p;
    return p;
}

// mirror-pair Phi11 (k3 = -g, +g), algebraically tightened.
// E0*rcp(kk0)^2 = L4*(1+u)^(-17/6) folded into caller's constant.
__device__ __forceinline__ float phi_pair(float k1, float k1sq, float n2k1, float Tt, float L2,
                                          float s, float sqs, float k2sc, float g) {
    const float kk   = fmaf(g, g, s);
    const float beta = Tt * __builtin_amdgcn_exp2f((-1.0f/3.0f) * __builtin_amdgcn_logf(L2 * kk));
    const float bk1  = beta * k1;
    const float Qh   = bk1 * g;
    const float xa   = kk - Qh, xb = kk + Qh;           // atan2 x-args
    const float sg   = 2.0f * s - kk;                   // s - g^2
    const float cc   = (bk1 * k1) * __builtin_amdgcn_rcpf(kk * s);
    const float C1a  = cc * (sg + Qh), C1b = cc * (sg - Qh);
    const float yv   = bk1 * sqs;
    const float tha  = atan2_pos(yv, xa);
    const float thb  = atan2_pos(yv, xb);
    const float R    = fmaf(bk1, bk1, kk);              // s + bk1^2 + g^2
    const float kk0a = fmaf(-2.0f, Qh, R), kk0b = fmaf(2.0f, Qh, R);
    const float ua   = L2 * kk0a, ub = L2 * kk0b;
    const float pa = __builtin_amdgcn_exp2f((-17.0f/6.0f) * __builtin_amdgcn_logf(1.0f + ua));
    const float pb = __builtin_amdgcn_exp2f((-17.0f/6.0f) * __builtin_amdgcn_logf(1.0f + ub));
    const float za = C1a - k2sc * (kk0a * tha);
    const float zb = C1b - k2sc * (kk0b * thb);
    const float k30a = bk1 - g, k30b = bk1 + g;
    const float qqa = fmaf(fmaf(s, za, n2k1 * k30a), za, kk0a - k1sq);
    const float qqb = fmaf(fmaf(s, zb, n2k1 * k30b), zb, kk0b - k1sq);
    return fmaf(pa, qqa, pb * qqb);
}

// ---------------- K1: phi image producer ----------------
// grid = 2048 blocks; block b handles (a = b>>2, chunk c = b&3).
// Writes 32x128 f16 swizzled image per block at img + b*4096 halfs.
__global__ __launch_bounds__(256, 4)
void phi_kernel(const float* __restrict__ k1_in,
                const float* __restrict__ plogL,
                const float* __restrict__ plogT,
                const float* __restrict__ plogM,
                _Float16* __restrict__ img)
{
    __shared__ float  s_grid[204];
    __shared__ float2 s_gw[204];

    const int t = threadIdx.x;
    const int b = blockIdx.x;
    const int a = b >> 2;
    const int c = b & 3;

    const float L  = expf(plogL[0]);
    const float Tt = expf(plogT[0]);
    const float M  = expf(plogM[0]);
    const float L2 = L * L;
    const float L4 = L2 * L2;
    const float k1   = k1_in[a];
    const float k1sq = k1 * k1;
    const float n2k1 = -2.0f * k1;
    const float rk1  = __builtin_amdgcn_rcpf(k1);
    const float cM0  = (M * 0.25f / PI_F) * PW_SCALE * L4;

    if (t < 204) {
        int tt = min(t, 200);
        float v;
        if (tt < 100)       v = -exp2f(LOG2_10 * (-4.0f + 8.0f * (float)(99 - tt) * (1.0f/99.0f)));
        else if (tt == 100) v = 0.0f;
        else                v =  exp2f(LOG2_10 * (-4.0f + 8.0f * (float)(tt - 101) * (1.0f/99.0f)));
        s_grid[t] = v;
    }
    __syncthreads();
    if (t < 204) {
        float wv = 0.0f;
        if (t == 0)          wv = 0.5f * (s_grid[1] - s_grid[0]);
        else if (t < 200)    wv = 0.5f * (s_grid[t+1] - s_grid[t-1]);
        else if (t == 200)   wv = 0.5f * (s_grid[200] - s_grid[199]);
        s_gw[t] = make_float2(s_grid[t], wv);
    }
    __syncthreads();

    _Float16* bimg = img + (size_t)b * 4096;

    if (c < 3) {
        const int il = t >> 3;        // row 0..31
        const int jb = t & 7;
        const int ii = c * 32 + il;   // <= 95, always active
        const float k2  = s_gw[100 + ii].x;
        const float w2m = s_gw[100 + ii].y * ((ii == 0) ? 1.0f : 2.0f);
        const float cM  = cM0 * w2m;
        const float s   = k1sq + k2 * k2;
        const float rs  = __builtin_amdgcn_rsqf(s);
        const float sqs = s * rs;
        const float k2sc = (k2 * rk1) * k2 * (rs * rs * rs);

        #pragma unroll 2
        for (int k = 0; k < 13; ++k) {
            const int jj = jb + (k << 3);          // 0..103
            const bool act = (jj <= 100);
            const float2 gwv = s_gw[100 + (act ? jj : 0)];
            float pws = phi_pair(k1, k1sq, n2k1, Tt, L2, s, sqs, k2sc, gwv.x);
            float w3s = (jj == 0) ? 0.5f * gwv.y : gwv.y;
            float val = act ? (pws * cM * w3s) : 0.0f;
            bimg[il * SP + (((jj >> 3) ^ (il & 7)) << 3) + (jj & 7)] = (_Float16)val;
        }
        // zero pad jj = 104..127
        #pragma unroll
        for (int m = 0; m < 3; ++m) {
            int jj = 104 + jb + (m << 3);
            bimg[il * SP + (((jj >> 3) ^ (il & 7)) << 3) + (jj & 7)] = (_Float16)0.0f;
        }
    } else {
        // chunk 3: rows ii=96..100 (il 0..4 active of 0..7); rows 8..31 zero-filled below
        const int il = t & 7;
        const int jb = t >> 3;        // 0..31
        const int ii = 96 + il;
        const bool rowAct = (ii <= 100);
        const int iic = min(ii, 100);
        const float k2  = s_gw[100 + iic].x;
        const float cM  = cM0 * (s_gw[100 + iic].y * 2.0f);
        const float s   = k1sq + k2 * k2;
        const float rs  = __builtin_amdgcn_rsqf(s);
        const float sqs = s * rs;
        const float k2sc = (k2 * rk1) * k2 * (rs * rs * rs);

        #pragma unroll
        for (int k = 0; k < 4; ++k) {
            const int jj = jb + (k << 5);          // 0..127
            const bool act = rowAct && (jj <= 100);
            const float2 gwv = s_gw[100 + min(jj, 100)];
            float pws = phi_pair(k1, k1sq, n2k1, Tt, L2, s, sqs, k2sc, gwv.x);
            float w3s = (jj == 0) ? 0.5f * gwv.y : gwv.y;
            float val = act ? (pws * cM * w3s) : 0.0f;
            bimg[il * SP + (((jj >> 3) ^ (il & 7)) << 3) + (jj & 7)] = (_Float16)val;
        }
        // zero rows 8..31 (24 rows x 128 halfs = 384 half8)
        {
            half8 zz = {};
            int base = 8 * SP;
            *(half8*)&bimg[base + t * 8] = zz;
            if (t < 128) *(half8*)&bimg[base + (t + 256) * 8] = zz;
        }
    }
}

// ---------------- K2: contraction kernel ----------------
__global__ __launch_bounds__(256, 3)
void spectral_kernel(const float* __restrict__ dy_in,
                     const float* __restrict__ dz_in,
                     const _Float16* __restrict__ img,
                     float* __restrict__ out)
{
    __shared__ __attribute__((aligned(16))) _Float16 s_phiT[32 * SP]; // A1 image (copied per chunk)
    __shared__ __attribute__((aligned(16))) _Float16 s_B3T[64 * SP];  // B1: [z][jj] cos (j-sym)
    __shared__ __attribute__((aligned(16))) _Float16 s_A2[64 * SA];   // A2: [y][ii]
    __shared__ __attribute__((aligned(16))) _Float16 s_TcT[64 * ST];  // B2: [z][ii-local]
    __shared__ float  s_grid[204];
    __shared__ float  s_dy[64], s_dz[64];
    __shared__ float  s_red[8];

    const int t    = threadIdx.x;
    const int a    = blockIdx.x;
    const int lane = t & 63;
    const int w    = t >> 6;       // wave id 0..3
    const int n16  = lane & 15;
    const int quad = lane >> 4;

    if (t < 204) {
        int tt = min(t, 200);
        float v;
        if (tt < 100)       v = -exp2f(LOG2_10 * (-4.0f + 8.0f * (float)(99 - tt) * (1.0f/99.0f)));
        else if (tt == 100) v = 0.0f;
        else                v =  exp2f(LOG2_10 * (-4.0f + 8.0f * (float)(tt - 101) * (1.0f/99.0f)));
        s_grid[t] = v;
    }
    if (t < 64) { s_dy[t] = dy_in[t]; s_dz[t] = dz_in[t]; }
    __syncthreads();

    // ---- B3T[z][jj] = cos(grid[100+jj]*dz[z]) f16, zero-pad jj>100 ----
    {
        const int jjp = lane;            // pair index; jj = 2*jjp, 2*jjp+1
        const int jj0 = 2 * jjp, jj1 = jj0 + 1;
        const float g0 = s_grid[min(100 + jj0, 203)];
        const float g1 = s_grid[min(100 + jj1, 203)];
        const int jjg  = jjp >> 2;
        for (int m = 0; m < 16; ++m) {
            int z = w + 4 * m;
            float dzr = s_dz[z] * INV2PI;
            float c0 = (jj0 <= 100) ? fast_cos(g0 * dzr) : 0.0f;
            float c1 = (jj1 <= 100) ? fast_cos(g1 * dzr) : 0.0f;
            half2v pr; pr.x = (_Float16)c0; pr.y = (_Float16)c1;
            *(half2v*)&s_B3T[z * SP + ((jjg ^ (z & 7)) << 3) + (jj0 & 7)] = pr;
        }
    }
    // ---- A2[y][ii] = cos(grid2[ii]*dy[y]) f16, zero-pad ii>100 ----
    {
        float dyr = s_dy[lane] * INV2PI;
        for (int k = 0; k < 16; ++k) {
            int iip = w + 4 * k;                // pair index 0..63
            int i0 = 2 * iip, i1 = i0 + 1;
            float c0 = (i0 <= 100) ? fast_cos(s_grid[min(100 + i0, 203)] * dyr) : 0.0f;
            float c1 = (i1 <= 100) ? fast_cos(s_grid[min(100 + i1, 203)] * dyr) : 0.0f;
            half2v pr; pr.x = (_Float16)c0; pr.y = (_Float16)c1;
            int off = lane * SA + (((iip >> 2) ^ (lane & 7)) << 3) + ((iip & 3) << 1);
            *(half2v*)&s_A2[off] = pr;
        }
    }
    __syncthreads();

    float f1 = 0.0f;
    f32x4 acc2[4];
    #pragma unroll
    for (int i = 0; i < 4; ++i) acc2[i] = (f32x4){0.f, 0.f, 0.f, 0.f};

    for (int c = 0; c < 4; ++c) {
        // ---- copy phi image chunk (8KB) global -> LDS; sum for F1 en route ----
        {
            const _Float16* src = img + ((size_t)(a * 4 + c) << 12);
            half8 v0 = *(const half8*)&src[t * 16];
            half8 v1 = *(const half8*)&src[t * 16 + 8];
            float sacc = 0.0f;
            #pragma unroll
            for (int e = 0; e < 8; ++e) sacc += (float)v0[e] + (float)v1[e];
            f1 += sacc;
            *(half8*)&s_phiT[t * 16]     = v0;
            *(half8*)&s_phiT[t * 16 + 8] = v1;
        }
        __syncthreads();   // phiT ready

        // ---- stage 1 (MFMA): TcT[z][ii] = sum_jj phiT[ii][jj]*B3T[z][jj], K=128 ----
        {
            const int mt  = w & 1;
            const int nt0 = (w >> 1) << 1;
            f32x4 acc1a = {0.f,0.f,0.f,0.f}, acc1b = {0.f,0.f,0.f,0.f};
            const int arow  = mt * 16 + n16;
            const int brow0 = nt0 * 16 + n16;
            const int brow1 = brow0 + 16;
            #pragma unroll
            for (int ks = 0; ks < 4; ++ks) {
                int kg = ks * 4 + quad;
                half8 af  = *(const half8*)&s_phiT[arow  * SP + ((kg ^ (arow  & 7)) << 3)];
                half8 bf0 = *(const half8*)&s_B3T [brow0 * SP + ((kg ^ (brow0 & 7)) << 3)];
                half8 bf1 = *(const half8*)&s_B3T [brow1 * SP + ((kg ^ (brow1 & 7)) << 3)];
                acc1a = __builtin_amdgcn_mfma_f32_16x16x32_f16(af, bf0, acc1a, 0, 0, 0);
                acc1b = __builtin_amdgcn_mfma_f32_16x16x32_f16(af, bf1, acc1b, 0, 0, 0);
            }
            const int ii0 = mt * 16 + quad * 4;
            const int gg  = ii0 >> 3;
            const int wi  = ii0 & 7;
            {
                int z = brow0;
                half4 hv; hv.x=(_Float16)acc1a.x; hv.y=(_Float16)acc1a.y;
                hv.z=(_Float16)acc1a.z; hv.w=(_Float16)acc1a.w;
                *(half4*)&s_TcT[z * ST + ((gg ^ (z & 7)) << 3) + wi] = hv;
            }
            {
                int z = brow1;
                half4 hv; hv.x=(_Float16)acc1b.x; hv.y=(_Float16)acc1b.y;
                hv.z=(_Float16)acc1b.z; hv.w=(_Float16)acc1b.w;
                *(half4*)&s_TcT[z * ST + ((gg ^ (z & 7)) << 3) + wi] = hv;
            }
        }
        __syncthreads();   // TcT ready

        // ---- stage 2 (MFMA): out[y][z] += A2[y][ii]*TcT[z][ii], K=32/chunk ----
        {
            const int yrow = w * 16 + n16;
            const int G = c * 4 + quad;
            half8 a2f = *(const half8*)&s_A2[yrow * SA + ((G ^ (yrow & 7)) << 3)];
            #pragma unroll
            for (int nt = 0; nt < 4; ++nt) {
                int z = nt * 16 + n16;
                half8 bf = *(const half8*)&s_TcT[z * ST + ((quad ^ (z & 7)) << 3)];
                acc2[nt] = __builtin_amdgcn_mfma_f32_16x16x32_f16(a2f, bf, acc2[nt], 0, 0, 0);
            }
        }
        __syncthreads();   // phiT/TcT reused next chunk
    }

    // ---- F1 block reduction -> 1/|F1| ----
    float v = f1;
    #pragma unroll
    for (int off = 32; off > 0; off >>= 1) v += __shfl_down(v, off, 64);
    if (lane == 0) s_red[w] = v;
    __syncthreads();
    if (t == 0) s_red[4] = 1.0f / fabsf(s_red[0] + s_red[1] + s_red[2] + s_red[3]);
    __syncthreads();
    const float rden = s_red[4];

    // ---- epilogue: D2 C-layout -> out[a][y][z] ----
    float* op = out + ((size_t)a << 12);
    #pragma unroll
    for (int nt = 0; nt < 4; ++nt) {
        int z = nt * 16 + n16;
        #pragma unroll
        for (int r = 0; r < 4; ++r) {
            int y = w * 16 + quad * 4 + r;
            op[y * 64 + z] = acc2[nt][r] * rden;
        }
    }
}

extern "C" void kernel_launch(void* const* d_in, const int* in_sizes, int n_in,
                              void* d_out, int out_size, void* d_ws, size_t ws_size,
                              hipStream_t stream) {
    const float* k1 = (const float*)d_in[0];
    const float* dy = (const float*)d_in[1];
    const float* dz = (const float*)d_in[2];
    const float* lL = (const float*)d_in[3];
    const float* lT = (const float*)d_in[4];
    const float* lM = (const float*)d_in[5];
    float* outp = (float*)d_out;
    _Float16* img = (_Float16*)d_ws;   // 512*4*4096 halfs = 16 MB

    hipLaunchKernelGGL(phi_kernel, dim3(2048), dim3(256), 0, stream,
                       k1, lL, lT, lM, img);
    hipLaunchKernelGGL(spectral_kernel, dim3(512), dim3(256), 0, stream,
                       dy, dz, img, outp);
}

// Round 7
// 89.233 us; speedup vs baseline: 1.0895x; 1.0895x over previous
//
#include <hip/hip_runtime.h>
#include <math.h>

#define BLOCK 256
#define LOG2_10 3.3219280948873623f
#define PI_F 3.14159265358979f
#define INV2PI 0.15915494309189535f
#define PW_SCALE 256.0f   // lifts Pw out of f16-subnormal range; cancels in out = num/F1

// LDS row strides in f16 elements
#define SP 128   // phiT / B3T: j folded 201->101, Kpad=128 (4 MFMA K-steps), 16 granules, XOR row&7
#define SA 128   // A2: 16 granules, XOR row&7
#define ST 64    // TcT: 8 granules, XOR row&7

typedef _Float16 half8 __attribute__((ext_vector_type(8)));
typedef _Float16 half4 __attribute__((ext_vector_type(4)));
typedef _Float16 half2v __attribute__((ext_vector_type(2)));
typedef float f32x4 __attribute__((ext_vector_type(4)));

__device__ __forceinline__ float fast_cos(float x_rev) {
    return __builtin_amdgcn_cosf(__builtin_amdgcn_fractf(x_rev));
}

// x^{-1/3} for normal positive x: integer magic + 2 Newton steps (full-rate VALU only)
__device__ __forceinline__ float rcbrt(float x) {
    unsigned i = __float_as_uint(x);
    i = 0x548c2b4bu - (unsigned)(((unsigned long long)i * 0xAAAAAAABull) >> 33);
    float y = __uint_as_float(i);
    const float xo3 = x * (1.0f / 3.0f);
    float y3 = y * y * y;
    y = y * fmaf(-xo3, y3, 1.33333333f);
    y3 = y * y * y;
    y = y * fmaf(-xo3, y3, 1.33333333f);
    return y;
}

__device__ __forceinline__ float atan2_pos(float y, float x) {
    // assumes y >= 0; returns atan2(y,x) in [0, pi]
    float ax = __builtin_fabsf(x);
    float mn = fminf(ax, y), mx = fmaxf(ax, y);
    float a = mn * __builtin_amdgcn_rcpf(mx);
    float t = a * a;
    float p = fmaf(fmaf(fmaf(fmaf(fmaf(-0.0117212f, t, 0.05265332f), t,
              -0.11643287f), t, 0.19354346f), t, -0.33262347f), t, 0.99997726f);
    p *= a;
    p = (y > ax) ? (1.57079632679f - p) : p;
    p = (x < 0.0f) ? (3.14159265359f - p) : p;
    return p;
}

// mirror-pair Phi11 (k3 = -g, +g). E0*rcp(kk0)^2 = L4*(1+u)^(-17/6) folded into caller's
// constant. All former log/exp pairs replaced by Newton rcbrt / rsq powers.
__device__ __forceinline__ float phi_pair(float k1, float k1sq, float n2k1, float Ttk1,
                                          float L2, float s, float sqs, float k2sc, float g) {
    const float kk   = fmaf(g, g, s);
    const float bk1  = Ttk1 * rcbrt(L2 * kk);           // beta*k1, no log/exp
    const float Qh   = bk1 * g;
    const float xa   = kk - Qh, xb = kk + Qh;           // atan2 x-args
    const float sg   = 2.0f * s - kk;                   // s - g^2
    const float cc   = (bk1 * k1) * __builtin_amdgcn_rcpf(kk * s);
    const float C1a  = cc * (sg + Qh), C1b = cc * (sg - Qh);
    const float yv   = bk1 * sqs;
    const float tha  = atan2_pos(yv, xa);
    const float thb  = atan2_pos(yv, xb);
    const float R    = fmaf(bk1, bk1, kk);              // s + bk1^2 + g^2
    const float kk0a = fmaf(-2.0f, Qh, R), kk0b = fmaf(2.0f, Qh, R);
    const float va   = fmaf(L2, kk0a, 1.0f);            // 1 + u
    const float vb   = fmaf(L2, kk0b, 1.0f);
    // (1+u)^{-17/6} = rsq^5 * rcbrt
    const float ra = __builtin_amdgcn_rsqf(va), rb = __builtin_amdgcn_rsqf(vb);
    const float ca = rcbrt(va),                cb = rcbrt(vb);
    const float ra2 = ra * ra, rb2 = rb * rb;
    const float pa = ra2 * ra2 * ra * ca;
    const float pb = rb2 * rb2 * rb * cb;
    const float za = C1a - k2sc * (kk0a * tha);
    const float zb = C1b - k2sc * (kk0b * thb);
    const float k30a = bk1 - g, k30b = bk1 + g;
    const float qqa = fmaf(fmaf(s, za, n2k1 * k30a), za, kk0a - k1sq);
    const float qqb = fmaf(fmaf(s, zb, n2k1 * k30b), zb, kk0b - k1sq);
    return fmaf(pa, qqa, pb * qqb);
}

__global__ __launch_bounds__(BLOCK, 2)
void spectral_kernel(const float* __restrict__ k1_in,
                     const float* __restrict__ dy_in,
                     const float* __restrict__ dz_in,
                     const float* __restrict__ plogL,
                     const float* __restrict__ plogT,
                     const float* __restrict__ plogM,
                     float* __restrict__ out)
{
    __shared__ __attribute__((aligned(16))) _Float16 s_phiT[32 * SP]; // A1: [ii][jj] pair sums
    __shared__ __attribute__((aligned(16))) _Float16 s_B3T[64 * SP];  // B1: [z][jj] cos (j-sym)
    __shared__ __attribute__((aligned(16))) _Float16 s_A2[64 * SA];   // A2: [y][ii]
    __shared__ __attribute__((aligned(16))) _Float16 s_TcT[64 * ST];  // B2: [z][ii-local]
    __shared__ float  s_grid[204];
    __shared__ float2 s_gw[204];     // {grid[j], trapz_w[j]}
    __shared__ float  s_dy[64], s_dz[64];
    __shared__ float  s_red[8];

    const int t    = threadIdx.x;
    const int a    = blockIdx.x;
    const int lane = t & 63;
    const int w    = t >> 6;       // wave id 0..3
    const int n16  = lane & 15;
    const int quad = lane >> 4;

    const float L  = expf(plogL[0]);
    const float Tt = expf(plogT[0]);
    const float M  = expf(plogM[0]);
    const float L2 = L * L;
    const float L4 = L2 * L2;
    const float k1   = k1_in[a];
    const float k1sq = k1 * k1;
    const float n2k1 = -2.0f * k1;
    const float Ttk1 = Tt * k1;
    const float rk1  = __builtin_amdgcn_rcpf(k1);
    const float cM0  = (M * 0.25f / PI_F) * PW_SCALE * L4;

    // ---- grid ----
    if (t < 204) {
        int tt = min(t, 200);
        float v;
        if (tt < 100)       v = -exp2f(LOG2_10 * (-4.0f + 8.0f * (float)(99 - tt) * (1.0f/99.0f)));
        else if (tt == 100) v = 0.0f;
        else                v =  exp2f(LOG2_10 * (-4.0f + 8.0f * (float)(tt - 101) * (1.0f/99.0f)));
        s_grid[t] = v;
    }
    if (t < 64) { s_dy[t] = dy_in[t]; s_dz[t] = dz_in[t]; }
    __syncthreads();

    // ---- trapz weights packed with grid ----
    if (t < 204) {
        float wv = 0.0f;
        if (t == 0)          wv = 0.5f * (s_grid[1] - s_grid[0]);
        else if (t < 200)    wv = 0.5f * (s_grid[t+1] - s_grid[t-1]);
        else if (t == 200)   wv = 0.5f * (s_grid[200] - s_grid[199]);
        s_gw[t] = make_float2(s_grid[t], wv);
    }
    // ---- B3T[z][jj] = cos(grid[100+jj]*dz[z]) f16, zero-pad jj>100 ----
    {
        const int jjp = lane;            // pair index; jj = 2*jjp, 2*jjp+1
        const int jj0 = 2 * jjp, jj1 = jj0 + 1;
        const float g0 = s_grid[min(100 + jj0, 203)];
        const float g1 = s_grid[min(100 + jj1, 203)];
        const int jjg  = jjp >> 2;
        for (int m = 0; m < 16; ++m) {
            int z = w + 4 * m;
            float dzr = s_dz[z] * INV2PI;
            float c0 = (jj0 <= 100) ? fast_cos(g0 * dzr) : 0.0f;
            float c1 = (jj1 <= 100) ? fast_cos(g1 * dzr) : 0.0f;
            half2v pr; pr.x = (_Float16)c0; pr.y = (_Float16)c1;
            *(half2v*)&s_B3T[z * SP + ((jjg ^ (z & 7)) << 3) + (jj0 & 7)] = pr;
        }
    }
    // ---- A2[y][ii] = cos(grid2[ii]*dy[y]) f16, zero-pad ii>100 ----
    {
        float dyr = s_dy[lane] * INV2PI;
        for (int k = 0; k < 16; ++k) {
            int iip = w + 4 * k;                // pair index 0..63
            int i0 = 2 * iip, i1 = i0 + 1;
            float c0 = (i0 <= 100) ? fast_cos(s_grid[min(100 + i0, 203)] * dyr) : 0.0f;
            float c1 = (i1 <= 100) ? fast_cos(s_grid[min(100 + i1, 203)] * dyr) : 0.0f;
            half2v pr; pr.x = (_Float16)c0; pr.y = (_Float16)c1;
            int off = lane * SA + (((iip >> 2) ^ (lane & 7)) << 3) + ((iip & 3) << 1);
            *(half2v*)&s_A2[off] = pr;
        }
    }
    // ---- zero phiT once (pad granules stay zero across chunks) ----
    {
        half8 zz = {};
        *(half8*)&s_phiT[t * 8] = zz;
        *(half8*)&s_phiT[(t + 256) * 8] = zz;
    }
    __syncthreads();

    float f1 = 0.0f;
    f32x4 acc2[4];
    #pragma unroll
    for (int i = 0; i < 4; ++i) acc2[i] = (f32x4){0.f, 0.f, 0.f, 0.f};

    const int il = t >> 3;        // phase-A ii-local row 0..31
    const int jb = t & 7;         // phase-A jj sub-index

    for (int c = 0; c < 4; ++c) {
        if (c < 3) {
            // ---- phase A: mirror-pair eval -> phiT[il][jj] ----
            const int ii = c * 32 + il;
            const float k2  = s_gw[100 + ii].x;
            const float w2m = s_gw[100 + ii].y * ((ii == 0) ? 1.0f : 2.0f);
            const float cM  = cM0 * w2m;
            const float s   = k1sq + k2 * k2;
            const float rs  = __builtin_amdgcn_rsqf(s);
            const float sqs = s * rs;
            const float k2sc = (k2 * rk1) * k2 * (rs * rs * rs);

            #pragma unroll 2
            for (int k = 0; k < 13; ++k) {
                const int jj = jb + (k << 3);          // 0..103
                const bool act = (jj <= 100);
                const float2 gwv = s_gw[100 + (act ? jj : 0)];
                float pws = phi_pair(k1, k1sq, n2k1, Ttk1, L2, s, sqs, k2sc, gwv.x);
                float w3s = (jj == 0) ? 0.5f * gwv.y : gwv.y;
                float val = act ? (pws * cM * w3s) : 0.0f;
                f1 += val;
                s_phiT[il * SP + (((jj >> 3) ^ (il & 7)) << 3) + (jj & 7)] = (_Float16)val;
            }
        } else {
            // ---- chunk 3: rows ii=96..100 only; zero rows 5..31, flatten 5x101 cells ----
            for (int idx = t; idx < 432; idx += 256) {
                half8 zz = {};
                *(half8*)&s_phiT[5 * SP + idx * 8] = zz;
            }
            #pragma unroll
            for (int m = 0; m < 2; ++m) {
                const int widx = t + 256 * m;
                if (widx < 505) {
                    const int il3 = widx / 101;
                    const int jj  = widx - il3 * 101;
                    const int ii  = 96 + il3;
                    const float k2  = s_gw[100 + ii].x;
                    const float cM  = cM0 * (s_gw[100 + ii].y * 2.0f);
                    const float s   = k1sq + k2 * k2;
                    const float rs  = __builtin_amdgcn_rsqf(s);
                    const float sqs = s * rs;
                    const float k2sc = (k2 * rk1) * k2 * (rs * rs * rs);
                    const float2 gwv = s_gw[100 + jj];
                    float pws = phi_pair(k1, k1sq, n2k1, Ttk1, L2, s, sqs, k2sc, gwv.x);
                    float w3s = (jj == 0) ? 0.5f * gwv.y : gwv.y;
                    float val = pws * cM * w3s;
                    f1 += val;
                    s_phiT[il3 * SP + (((jj >> 3) ^ (il3 & 7)) << 3) + (jj & 7)] = (_Float16)val;
                }
            }
        }
        __syncthreads();   // B1: phiT ready

        // ---- stage 1 (MFMA): TcT[z][ii] = sum_jj phiT[ii][jj]*B3T[z][jj], K=128 ----
        {
            const int mt  = w & 1;
            const int nt0 = (w >> 1) << 1;
            f32x4 acc1a = {0.f,0.f,0.f,0.f}, acc1b = {0.f,0.f,0.f,0.f};
            const int arow  = mt * 16 + n16;
            const int brow0 = nt0 * 16 + n16;
            const int brow1 = brow0 + 16;
            #pragma unroll
            for (int ks = 0; ks < 4; ++ks) {
                int kg = ks * 4 + quad;
                half8 af  = *(const half8*)&s_phiT[arow  * SP + ((kg ^ (arow  & 7)) << 3)];
                half8 bf0 = *(const half8*)&s_B3T [brow0 * SP + ((kg ^ (brow0 & 7)) << 3)];
                half8 bf1 = *(const half8*)&s_B3T [brow1 * SP + ((kg ^ (brow1 & 7)) << 3)];
                acc1a = __builtin_amdgcn_mfma_f32_16x16x32_f16(af, bf0, acc1a, 0, 0, 0);
                acc1b = __builtin_amdgcn_mfma_f32_16x16x32_f16(af, bf1, acc1b, 0, 0, 0);
            }
            const int ii0 = mt * 16 + quad * 4;
            const int gg  = ii0 >> 3;
            const int wi  = ii0 & 7;
            {
                int z = brow0;
                half4 hv; hv.x=(_Float16)acc1a.x; hv.y=(_Float16)acc1a.y;
                hv.z=(_Float16)acc1a.z; hv.w=(_Float16)acc1a.w;
                *(half4*)&s_TcT[z * ST + ((gg ^ (z & 7)) << 3) + wi] = hv;
            }
            {
                int z = brow1;
                half4 hv; hv.x=(_Float16)acc1b.x; hv.y=(_Float16)acc1b.y;
                hv.z=(_Float16)acc1b.z; hv.w=(_Float16)acc1b.w;
                *(half4*)&s_TcT[z * ST + ((gg ^ (z & 7)) << 3) + wi] = hv;
            }
        }
        __syncthreads();   // B2: TcT ready

        // ---- stage 2 (MFMA): out[y][z] += A2[y][ii]*TcT[z][ii], K=32/chunk ----
        {
            const int yrow = w * 16 + n16;
            const int G = c * 4 + quad;
            half8 a2f = *(const half8*)&s_A2[yrow * SA + ((G ^ (yrow & 7)) << 3)];
            #pragma unroll
            for (int nt = 0; nt < 4; ++nt) {
                int z = nt * 16 + n16;
                half8 bf = *(const half8*)&s_TcT[z * ST + ((quad ^ (z & 7)) << 3)];
                acc2[nt] = __builtin_amdgcn_mfma_f32_16x16x32_f16(a2f, bf, acc2[nt], 0, 0, 0);
            }
        }
        __syncthreads();   // phiT/TcT reused next chunk
    }

    // ---- F1 block reduction -> 1/|F1| ----
    float v = f1;
    #pragma unroll
    for (int off = 32; off > 0; off >>= 1) v += __shfl_down(v, off, 64);
    if (lane == 0) s_red[w] = v;
    __syncthreads();
    if (t == 0) s_red[4] = 1.0f / fabsf(s_red[0] + s_red[1] + s_red[2] + s_red[3]);
    __syncthreads();
    const float rden = s_red[4];

    // ---- epilogue: D2 C-layout -> out[a][y][z] ----
    float* op = out + ((size_t)a << 12);
    #pragma unroll
    for (int nt = 0; nt < 4; ++nt) {
        int z = nt * 16 + n16;
        #pragma unroll
        for (int r = 0; r < 4; ++r) {
            int y = w * 16 + quad * 4 + r;
            op[y * 64 + z] = acc2[nt][r] * rden;
        }
    }
}

extern "C" void kernel_launch(void* const* d_in, const int* in_sizes, int n_in,
                              void* d_out, int out_size, void* d_ws, size_t ws_size,
                              hipStream_t stream) {
    const float* k1 = (const float*)d_in[0];
    const float* dy = (const float*)d_in[1];
    const float* dz = (const float*)d_in[2];
    const float* lL = (const float*)d_in[3];
    const float* lT = (const float*)d_in[4];
    const float* lM = (const float*)d_in[5];
    float* outp = (float*)d_out;
    hipLaunchKernelGGL(spectral_kernel, dim3(512), dim3(BLOCK), 0, stream,
                       k1, dy, dz, lL, lT, lM, outp);
}

// Round 9
// 82.957 us; speedup vs baseline: 1.1719x; 1.0756x over previous
//
#include <hip/hip_runtime.h>
#include <math.h>

#define BLOCK 256
#define LOG2_10 3.3219280948873623f
#define PI_F 3.14159265358979f
#define INV2PI 0.15915494309189535f
#define PW_SCALE 256.0f   // lifts Pw out of f16-subnormal range; cancels in out = num/F1

// LDS row strides in f16 elements
#define SP 128   // phiT / B3T: j folded 201->101, Kpad=128 (4 MFMA K-steps), 16 granules, XOR row&7
#define SA 128   // A2: 16 granules, XOR row&7
#define ST 64    // TcT: 8 granules, XOR row&7

typedef _Float16 half8 __attribute__((ext_vector_type(8)));
typedef _Float16 half4 __attribute__((ext_vector_type(4)));
typedef _Float16 half2v __attribute__((ext_vector_type(2)));
typedef float f32x4 __attribute__((ext_vector_type(4)));
typedef float v2f  __attribute__((ext_vector_type(2)));

__device__ __forceinline__ v2f v2(float a, float b) { v2f r; r.x = a; r.y = b; return r; }

__device__ __forceinline__ float fast_cos(float x_rev) {
    return __builtin_amdgcn_cosf(__builtin_amdgcn_fractf(x_rev));
}

// packed atan2 for y >= 0 (y shared by both elements); result in [0, pi]
__device__ __forceinline__ v2f atan2_pos_pk(float yv, v2f x) {
    float ax0 = __builtin_fabsf(x.x), ax1 = __builtin_fabsf(x.y);
    float mn0 = fminf(ax0, yv), mx0 = fmaxf(ax0, yv);
    float mn1 = fminf(ax1, yv), mx1 = fmaxf(ax1, yv);
    v2f a = v2(mn0 * __builtin_amdgcn_rcpf(mx0), mn1 * __builtin_amdgcn_rcpf(mx1));
    v2f t = a * a;
    v2f p = ((((( -0.0117212f * t + 0.05265332f) * t - 0.11643287f) * t
              + 0.19354346f) * t - 0.33262347f) * t + 0.99997726f) * a;
    float p0 = (yv > ax0) ? (1.57079632679f - p.x) : p.x;
    float p1 = (yv > ax1) ? (1.57079632679f - p.y) : p.y;
    p0 = (x.x < 0.0f) ? (3.14159265359f - p0) : p0;
    p1 = (x.y < 0.0f) ? (3.14159265359f - p1) : p1;
    return v2(p0, p1);
}

// mirror-pair Phi11 (k3 = -g, +g); a/b sides packed as float2 lanes.
// E0*rcp(kk0)^2 = L4*(1+u)^(-17/6), L4 folded into caller's constant.
__device__ __forceinline__ float phi_pair_pk(float k1, float k1sq, float n2k1, float Ttk1,
                                             float L2, float s, float sqs, float k2sc, float g) {
    const float kk  = g * g + s;
    const float bk1 = Ttk1 * __builtin_amdgcn_exp2f((-1.0f/3.0f) * __builtin_amdgcn_logf(L2 * kk));
    const float Qh  = bk1 * g;
    const float sg  = 2.0f * s - kk;                    // s - g^2
    const float cc  = (bk1 * k1) * __builtin_amdgcn_rcpf(kk * s);
    const float yv  = bk1 * sqs;
    const float R   = bk1 * bk1 + kk;                   // s + bk1^2 + g^2
    const v2f x   = v2(kk - Qh, kk + Qh);
    const v2f C1  = cc * v2(sg + Qh, sg - Qh);
    const v2f kk0 = v2(R - 2.0f * Qh, R + 2.0f * Qh);
    const v2f th  = atan2_pos_pk(yv, x);
    const v2f vv  = L2 * kk0 + 1.0f;                    // 1 + u
    const v2f p   = v2(__builtin_amdgcn_exp2f((-17.0f/6.0f) * __builtin_amdgcn_logf(vv.x)),
                       __builtin_amdgcn_exp2f((-17.0f/6.0f) * __builtin_amdgcn_logf(vv.y)));
    const v2f z   = C1 - k2sc * (kk0 * th);
    const v2f k30 = v2(bk1 - g, bk1 + g);
    const v2f qq  = (s * z + n2k1 * k30) * z + (kk0 - k1sq);
    const v2f r   = p * qq;
    return r.x + r.y;
}

__global__ __launch_bounds__(BLOCK, 2)
void spectral_kernel(const float* __restrict__ k1_in,
                     const float* __restrict__ dy_in,
                     const float* __restrict__ dz_in,
                     const float* __restrict__ plogL,
                     const float* __restrict__ plogT,
                     const float* __restrict__ plogM,
                     float* __restrict__ out)
{
    __shared__ __attribute__((aligned(16))) _Float16 s_phiT[32 * SP]; // A1: [ii][jj] pair sums
    __shared__ __attribute__((aligned(16))) _Float16 s_B3T[64 * SP];  // B1: [z][jj] cos (j-sym)
    __shared__ __attribute__((aligned(16))) _Float16 s_A2[64 * SA];   // A2: [y][ii]
    __shared__ __attribute__((aligned(16))) _Float16 s_TcT[64 * ST];  // B2: [z][ii-local]
    __shared__ float  s_grid[204];
    __shared__ float2 s_gw[204];     // {grid[j], trapz_w[j]}
    __shared__ float  s_dy[64], s_dz[64];
    __shared__ float  s_red[8];

    const int t    = threadIdx.x;
    const int a    = blockIdx.x;
    const int lane = t & 63;
    const int w    = t >> 6;       // wave id 0..3
    const int n16  = lane & 15;
    const int quad = lane >> 4;

    const float L  = expf(plogL[0]);
    const float Tt = expf(plogT[0]);
    const float M  = expf(plogM[0]);
    const float L2 = L * L;
    const float L4 = L2 * L2;
    const float k1   = k1_in[a];
    const float k1sq = k1 * k1;
    const float n2k1 = -2.0f * k1;
    const float Ttk1 = Tt * k1;
    const float rk1  = __builtin_amdgcn_rcpf(k1);
    const float cM0  = (M * 0.25f / PI_F) * PW_SCALE * L4;

    // ---- grid ----
    if (t < 204) {
        int tt = min(t, 200);
        float v;
        if (tt < 100)       v = -exp2f(LOG2_10 * (-4.0f + 8.0f * (float)(99 - tt) * (1.0f/99.0f)));
        else if (tt == 100) v = 0.0f;
        else                v =  exp2f(LOG2_10 * (-4.0f + 8.0f * (float)(tt - 101) * (1.0f/99.0f)));
        s_grid[t] = v;
    }
    if (t < 64) { s_dy[t] = dy_in[t]; s_dz[t] = dz_in[t]; }
    __syncthreads();

    // ---- trapz weights packed with grid ----
    if (t < 204) {
        float wv = 0.0f;
        if (t == 0)          wv = 0.5f * (s_grid[1] - s_grid[0]);
        else if (t < 200)    wv = 0.5f * (s_grid[t+1] - s_grid[t-1]);
        else if (t == 200)   wv = 0.5f * (s_grid[200] - s_grid[199]);
        s_gw[t] = make_float2(s_grid[t], wv);
    }
    // ---- B3T[z][jj] = cos(grid[100+jj]*dz[z]) f16, zero-pad jj>100 ----
    {
        const int jjp = lane;            // pair index; jj = 2*jjp, 2*jjp+1
        const int jj0 = 2 * jjp, jj1 = jj0 + 1;
        const float g0 = s_grid[min(100 + jj0, 203)];
        const float g1 = s_grid[min(100 + jj1, 203)];
        const int jjg  = jjp >> 2;
        for (int m = 0; m < 16; ++m) {
            int z = w + 4 * m;
            float dzr = s_dz[z] * INV2PI;
            float c0 = (jj0 <= 100) ? fast_cos(g0 * dzr) : 0.0f;
            float c1 = (jj1 <= 100) ? fast_cos(g1 * dzr) : 0.0f;
            half2v pr; pr.x = (_Float16)c0; pr.y = (_Float16)c1;
            *(half2v*)&s_B3T[z * SP + ((jjg ^ (z & 7)) << 3) + (jj0 & 7)] = pr;
        }
    }
    // ---- A2[y][ii] = cos(grid2[ii]*dy[y]) f16, zero-pad ii>100 ----
    {
        float dyr = s_dy[lane] * INV2PI;
        for (int k = 0; k < 16; ++k) {
            int iip = w + 4 * k;                // pair index 0..63
            int i0 = 2 * iip, i1 = i0 + 1;
            float c0 = (i0 <= 100) ? fast_cos(s_grid[min(100 + i0, 203)] * dyr) : 0.0f;
            float c1 = (i1 <= 100) ? fast_cos(s_grid[min(100 + i1, 203)] * dyr) : 0.0f;
            half2v pr; pr.x = (_Float16)c0; pr.y = (_Float16)c1;
            int off = lane * SA + (((iip >> 2) ^ (lane & 7)) << 3) + ((iip & 3) << 1);
            *(half2v*)&s_A2[off] = pr;
        }
    }
    // ---- zero phiT once (pad granules stay zero across chunks) ----
    {
        half8 zz = {};
        *(half8*)&s_phiT[t * 8] = zz;
        *(half8*)&s_phiT[(t + 256) * 8] = zz;
    }
    __syncthreads();

    float f1 = 0.0f;
    f32x4 acc2[4];
    #pragma unroll
    for (int i = 0; i < 4; ++i) acc2[i] = (f32x4){0.f, 0.f, 0.f, 0.f};

    const int il = t >> 3;        // phase-A ii-local row 0..31
    const int jb = t & 7;         // phase-A jj sub-index

    // ---- hoist jj-dependent grid values to registers (reused by all chunks);
    //      act-mask folded into w3r (=0 for jj>100, halved at jj==0) ----
    float gr[13], w3r[13];
    #pragma unroll
    for (int k = 0; k < 13; ++k) {
        const int jj = jb + (k << 3);          // 0..103
        const float2 gwv = s_gw[100 + min(jj, 100)];
        gr[k]  = gwv.x;
        w3r[k] = (jj == 0) ? 0.5f * gwv.y : ((jj <= 100) ? gwv.y : 0.0f);
    }

    for (int c = 0; c < 4; ++c) {
        if (c < 3) {
            // ---- phase A: packed mirror-pair eval -> phiT[il][jj] ----
            const int ii = c * 32 + il;
            const float k2  = s_gw[100 + ii].x;
            const float w2m = s_gw[100 + ii].y * ((ii == 0) ? 1.0f : 2.0f);
            const float cM  = cM0 * w2m;
            const float s   = k1sq + k2 * k2;
            const float rs  = __builtin_amdgcn_rsqf(s);
            const float sqs = s * rs;
            const float k2sc = (k2 * rk1) * k2 * (rs * rs * rs);

            #pragma unroll
            for (int k = 0; k < 13; ++k) {
                float pws = phi_pair_pk(k1, k1sq, n2k1, Ttk1, L2, s, sqs, k2sc, gr[k]);
                float val = pws * (cM * w3r[k]);
                f1 += val;
                // granule = (jj>>3) ^ (il&7) = k ^ (il&7), 4-bit (k up to 12) — do NOT mask to 3 bits
                s_phiT[il * SP + ((k ^ (il & 7)) << 3) + jb] = (_Float16)val;
            }
        } else {
            // ---- chunk 3: rows ii=96..100 only; zero rows 5..31, flatten 5x101 cells ----
            for (int idx = t; idx < 432; idx += 256) {
                half8 zz = {};
                *(half8*)&s_phiT[5 * SP + idx * 8] = zz;
            }
            #pragma unroll
            for (int m = 0; m < 2; ++m) {
                const int widx = t + 256 * m;
                if (widx < 505) {
                    const int il3 = widx / 101;
                    const int jj  = widx - il3 * 101;
                    const int ii  = 96 + il3;
                    const float k2  = s_gw[100 + ii].x;
                    const float cM  = cM0 * (s_gw[100 + ii].y * 2.0f);
                    const float s   = k1sq + k2 * k2;
                    const float rs  = __builtin_amdgcn_rsqf(s);
                    const float sqs = s * rs;
                    const float k2sc = (k2 * rk1) * k2 * (rs * rs * rs);
                    const float2 gwv = s_gw[100 + jj];
                    float pws = phi_pair_pk(k1, k1sq, n2k1, Ttk1, L2, s, sqs, k2sc, gwv.x);
                    float w3s = (jj == 0) ? 0.5f * gwv.y : gwv.y;
                    float val = pws * cM * w3s;
                    f1 += val;
                    s_phiT[il3 * SP + (((jj >> 3) ^ (il3 & 7)) << 3) + (jj & 7)] = (_Float16)val;
                }
            }
        }
        __syncthreads();   // B1: phiT ready

        // ---- stage 1 (MFMA): TcT[z][ii] = sum_jj phiT[ii][jj]*B3T[z][jj], K=128 ----
        {
            const int mt  = w & 1;
            const int nt0 = (w >> 1) << 1;
            f32x4 acc1a = {0.f,0.f,0.f,0.f}, acc1b = {0.f,0.f,0.f,0.f};
            const int arow  = mt * 16 + n16;
            const int brow0 = nt0 * 16 + n16;
            const int brow1 = brow0 + 16;
            #pragma unroll
            for (int ks = 0; ks < 4; ++ks) {
                int kg = ks * 4 + quad;
                half8 af  = *(const half8*)&s_phiT[arow  * SP + ((kg ^ (arow  & 7)) << 3)];
                half8 bf0 = *(const half8*)&s_B3T [brow0 * SP + ((kg ^ (brow0 & 7)) << 3)];
                half8 bf1 = *(const half8*)&s_B3T [brow1 * SP + ((kg ^ (brow1 & 7)) << 3)];
                acc1a = __builtin_amdgcn_mfma_f32_16x16x32_f16(af, bf0, acc1a, 0, 0, 0);
                acc1b = __builtin_amdgcn_mfma_f32_16x16x32_f16(af, bf1, acc1b, 0, 0, 0);
            }
            const int ii0 = mt * 16 + quad * 4;
            const int gg  = ii0 >> 3;
            const int wi  = ii0 & 7;
            {
                int z = brow0;
                half4 hv; hv.x=(_Float16)acc1a.x; hv.y=(_Float16)acc1a.y;
                hv.z=(_Float16)acc1a.z; hv.w=(_Float16)acc1a.w;
                *(half4*)&s_TcT[z * ST + ((gg ^ (z & 7)) << 3) + wi] = hv;
            }
            {
                int z = brow1;
                half4 hv; hv.x=(_Float16)acc1b.x; hv.y=(_Float16)acc1b.y;
                hv.z=(_Float16)acc1b.z; hv.w=(_Float16)acc1b.w;
                *(half4*)&s_TcT[z * ST + ((gg ^ (z & 7)) << 3) + wi] = hv;
            }
        }
        __syncthreads();   // B2: TcT ready

        // ---- stage 2 (MFMA): out[y][z] += A2[y][ii]*TcT[z][ii], K=32/chunk ----
        {
            const int yrow = w * 16 + n16;
            const int G = c * 4 + quad;
            half8 a2f = *(const half8*)&s_A2[yrow * SA + ((G ^ (yrow & 7)) << 3)];
            #pragma unroll
            for (int nt = 0; nt < 4; ++nt) {
                int z = nt * 16 + n16;
                half8 bf = *(const half8*)&s_TcT[z * ST + ((quad ^ (z & 7)) << 3)];
                acc2[nt] = __builtin_amdgcn_mfma_f32_16x16x32_f16(a2f, bf, acc2[nt], 0, 0, 0);
            }
        }
        __syncthreads();   // phiT/TcT reused next chunk
    }

    // ---- F1 block reduction -> 1/|F1| ----
    float v = f1;
    #pragma unroll
    for (int off = 32; off > 0; off >>= 1) v += __shfl_down(v, off, 64);
    if (lane == 0) s_red[w] = v;
    __syncthreads();
    if (t == 0) s_red[4] = 1.0f / fabsf(s_red[0] + s_red[1] + s_red[2] + s_red[3]);
    __syncthreads();
    const float rden = s_red[4];

    // ---- epilogue: D2 C-layout -> out[a][y][z] ----
    float* op = out + ((size_t)a << 12);
    #pragma unroll
    for (int nt = 0; nt < 4; ++nt) {
        int z = nt * 16 + n16;
        #pragma unroll
        for (int r = 0; r < 4; ++r) {
            int y = w * 16 + quad * 4 + r;
            op[y * 64 + z] = acc2[nt][r] * rden;
        }
    }
}

extern "C" void kernel_launch(void* const* d_in, const int* in_sizes, int n_in,
                              void* d_out, int out_size, void* d_ws, size_t ws_size,
                              hipStream_t stream) {
    const float* k1 = (const float*)d_in[0];
    const float* dy = (const float*)d_in[1];
    const float* dz = (const float*)d_in[2];
    const float* lL = (const float*)d_in[3];
    const float* lT = (const float*)d_in[4];
    const float* lM = (const float*)d_in[5];
    float* outp = (float*)d_out;
    hipLaunchKernelGGL(spectral_kernel, dim3(512), dim3(BLOCK), 0, stream,
                       k1, dy, dz, lL, lT, lM, outp);
}

// Round 10
// 79.555 us; speedup vs baseline: 1.2220x; 1.0428x over previous
//
#include <hip/hip_runtime.h>
#include <math.h>

#define BLOCK 256
#define LOG2_10 3.3219280948873623f
#define PI_F 3.14159265358979f
#define INV2PI 0.15915494309189535f
#define PW_SCALE 256.0f   // lifts Pw out of f16-subnormal range; cancels in out = num/F1

// LDS row strides in f16 elements
#define SP 128   // phiT / B3T: j folded 201->101, K used = 96 (3 MFMA K-steps); XOR row&7 swizzle
#define SA 128   // A2: 16 granules, XOR row&7
#define ST 64    // TcT: 8 granules, XOR row&7

typedef _Float16 half8 __attribute__((ext_vector_type(8)));
typedef _Float16 half4 __attribute__((ext_vector_type(4)));
typedef _Float16 half2v __attribute__((ext_vector_type(2)));
typedef float f32x4 __attribute__((ext_vector_type(4)));
typedef float v2f  __attribute__((ext_vector_type(2)));

__device__ __forceinline__ v2f v2(float a, float b) { v2f r; r.x = a; r.y = b; return r; }

__device__ __forceinline__ float fast_cos(float x_rev) {
    return __builtin_amdgcn_cosf(__builtin_amdgcn_fractf(x_rev));
}

// packed atan2 for y >= 0 (y shared by both elements); result in [0, pi]
__device__ __forceinline__ v2f atan2_pos_pk(float yv, v2f x) {
    float ax0 = __builtin_fabsf(x.x), ax1 = __builtin_fabsf(x.y);
    float mn0 = fminf(ax0, yv), mx0 = fmaxf(ax0, yv);
    float mn1 = fminf(ax1, yv), mx1 = fmaxf(ax1, yv);
    v2f a = v2(mn0 * __builtin_amdgcn_rcpf(mx0), mn1 * __builtin_amdgcn_rcpf(mx1));
    v2f t = a * a;
    v2f p = ((((( -0.0117212f * t + 0.05265332f) * t - 0.11643287f) * t
              + 0.19354346f) * t - 0.33262347f) * t + 0.99997726f) * a;
    float p0 = (yv > ax0) ? (1.57079632679f - p.x) : p.x;
    float p1 = (yv > ax1) ? (1.57079632679f - p.y) : p.y;
    p0 = (x.x < 0.0f) ? (3.14159265359f - p0) : p0;
    p1 = (x.y < 0.0f) ? (3.14159265359f - p1) : p1;
    return v2(p0, p1);
}

// mirror-pair Phi11 (k3 = -g, +g); a/b sides packed as float2 lanes.
// E0*rcp(kk0)^2 = L4*(1+u)^(-17/6), L4 folded into caller's constant.
__device__ __forceinline__ float phi_pair_pk(float k1, float k1sq, float n2k1, float Ttk1,
                                             float L2, float s, float sqs, float k2sc, float g) {
    const float kk  = g * g + s;
    const float bk1 = Ttk1 * __builtin_amdgcn_exp2f((-1.0f/3.0f) * __builtin_amdgcn_logf(L2 * kk));
    const float Qh  = bk1 * g;
    const float sg  = 2.0f * s - kk;                    // s - g^2
    const float cc  = (bk1 * k1) * __builtin_amdgcn_rcpf(kk * s);
    const float yv  = bk1 * sqs;
    const float R   = bk1 * bk1 + kk;                   // s + bk1^2 + g^2
    const v2f x   = v2(kk - Qh, kk + Qh);
    const v2f C1  = cc * v2(sg + Qh, sg - Qh);
    const v2f kk0 = v2(R - 2.0f * Qh, R + 2.0f * Qh);
    const v2f th  = atan2_pos_pk(yv, x);
    const v2f vv  = L2 * kk0 + 1.0f;                    // 1 + u
    const v2f p   = v2(__builtin_amdgcn_exp2f((-17.0f/6.0f) * __builtin_amdgcn_logf(vv.x)),
                       __builtin_amdgcn_exp2f((-17.0f/6.0f) * __builtin_amdgcn_logf(vv.y)));
    const v2f z   = C1 - k2sc * (kk0 * th);
    const v2f k30 = v2(bk1 - g, bk1 + g);
    const v2f qq  = (s * z + n2k1 * k30) * z + (kk0 - k1sq);
    const v2f r   = p * qq;
    return r.x + r.y;
}

// far-field (beta->0) pair: valid to <f16-ulp when max(k2,g) index >= 80 (r >= ~240)
__device__ __forceinline__ float phi_pair_cheap(float k1sq, float L2, float s, float g) {
    const float kk = g * g + s;
    const float p  = __builtin_amdgcn_exp2f((-17.0f/6.0f) *
                     __builtin_amdgcn_logf(fmaf(L2, kk, 1.0f)));
    return 2.0f * p * (kk - k1sq);
}

__global__ __launch_bounds__(BLOCK, 2)
void spectral_kernel(const float* __restrict__ k1_in,
                     const float* __restrict__ dy_in,
                     const float* __restrict__ dz_in,
                     const float* __restrict__ plogL,
                     const float* __restrict__ plogT,
                     const float* __restrict__ plogM,
                     float* __restrict__ out)
{
    __shared__ __attribute__((aligned(16))) _Float16 s_phiT[32 * SP]; // A1: [ii][jj] pair sums
    __shared__ __attribute__((aligned(16))) _Float16 s_B3T[64 * SP];  // B1: [z][jj] cos (j-sym)
    __shared__ __attribute__((aligned(16))) _Float16 s_A2[64 * SA];   // A2: [y][ii]
    __shared__ __attribute__((aligned(16))) _Float16 s_TcT[64 * ST];  // B2: [z][ii-local]
    __shared__ float  s_grid[204];
    __shared__ float2 s_gw[204];     // {grid[j], trapz_w[j]}
    __shared__ float  s_dy[64], s_dz[64];
    __shared__ float  s_red[8];

    const int t    = threadIdx.x;
    const int a    = blockIdx.x;
    const int lane = t & 63;
    const int w    = t >> 6;       // wave id 0..3
    const int n16  = lane & 15;
    const int quad = lane >> 4;

    const float L  = expf(plogL[0]);
    const float Tt = expf(plogT[0]);
    const float M  = expf(plogM[0]);
    const float L2 = L * L;
    const float L4 = L2 * L2;
    const float k1   = k1_in[a];
    const float k1sq = k1 * k1;
    const float n2k1 = -2.0f * k1;
    const float Ttk1 = Tt * k1;
    const float rk1  = __builtin_amdgcn_rcpf(k1);
    const float cM0  = (M * 0.25f / PI_F) * PW_SCALE * L4;

    // ---- grid ----
    if (t < 204) {
        int tt = min(t, 200);
        float v;
        if (tt < 100)       v = -exp2f(LOG2_10 * (-4.0f + 8.0f * (float)(99 - tt) * (1.0f/99.0f)));
        else if (tt == 100) v = 0.0f;
        else                v =  exp2f(LOG2_10 * (-4.0f + 8.0f * (float)(tt - 101) * (1.0f/99.0f)));
        s_grid[t] = v;
    }
    if (t < 64) { s_dy[t] = dy_in[t]; s_dz[t] = dz_in[t]; }
    __syncthreads();

    // ---- trapz weights packed with grid ----
    if (t < 204) {
        float wv = 0.0f;
        if (t == 0)          wv = 0.5f * (s_grid[1] - s_grid[0]);
        else if (t < 200)    wv = 0.5f * (s_grid[t+1] - s_grid[t-1]);
        else if (t == 200)   wv = 0.5f * (s_grid[200] - s_grid[199]);
        s_gw[t] = make_float2(s_grid[t], wv);
    }
    // ---- B3T[z][jj] = cos(grid[100+jj]*dz[z]) f16, zero-pad jj>100 ----
    {
        const int jjp = lane;            // pair index; jj = 2*jjp, 2*jjp+1
        const int jj0 = 2 * jjp, jj1 = jj0 + 1;
        const float g0 = s_grid[min(100 + jj0, 203)];
        const float g1 = s_grid[min(100 + jj1, 203)];
        const int jjg  = jjp >> 2;
        for (int m = 0; m < 16; ++m) {
            int z = w + 4 * m;
            float dzr = s_dz[z] * INV2PI;
            float c0 = (jj0 <= 100) ? fast_cos(g0 * dzr) : 0.0f;
            float c1 = (jj1 <= 100) ? fast_cos(g1 * dzr) : 0.0f;
            half2v pr; pr.x = (_Float16)c0; pr.y = (_Float16)c1;
            *(half2v*)&s_B3T[z * SP + ((jjg ^ (z & 7)) << 3) + (jj0 & 7)] = pr;
        }
    }
    // ---- A2[y][ii] = cos(grid2[ii]*dy[y]) f16, zero-pad ii>100 ----
    {
        float dyr = s_dy[lane] * INV2PI;
        for (int k = 0; k < 16; ++k) {
            int iip = w + 4 * k;                // pair index 0..63
            int i0 = 2 * iip, i1 = i0 + 1;
            float c0 = (i0 <= 100) ? fast_cos(s_grid[min(100 + i0, 203)] * dyr) : 0.0f;
            float c1 = (i1 <= 100) ? fast_cos(s_grid[min(100 + i1, 203)] * dyr) : 0.0f;
            half2v pr; pr.x = (_Float16)c0; pr.y = (_Float16)c1;
            int off = lane * SA + (((iip >> 2) ^ (lane & 7)) << 3) + ((iip & 3) << 1);
            *(half2v*)&s_A2[off] = pr;
        }
    }
    __syncthreads();

    float f1 = 0.0f;
    f32x4 acc2[4];
    #pragma unroll
    for (int i = 0; i < 4; ++i) acc2[i] = (f32x4){0.f, 0.f, 0.f, 0.f};

    const int il = t >> 3;        // phase-A ii-local row 0..31
    const int jb = t & 7;         // phase-A jj sub-index

    // ---- hoist jj-dependent grid values (k 0..10 -> jj 0..87, all <= 100) ----
    float gr[11], w3r[11];
    #pragma unroll
    for (int k = 0; k < 11; ++k) {
        const int jj = jb + (k << 3);
        const float2 gwv = s_gw[100 + jj];
        gr[k]  = gwv.x;
        w3r[k] = (jj == 0) ? 0.5f * gwv.y : gwv.y;
    }

    for (int c = 0; c < 3; ++c) {    // ii 96..100 are f16-zero -> chunk 3 dropped entirely
        // ---- phase A: mirror-pair eval -> phiT[il][jj] (logical granules 0..11) ----
        {
            const int ii = c * 32 + il;
            const bool cheapRow = (ii >= 80);   // wave-uniform: far-field beta->0 valid
            const bool zeroRow  = (ii >= 88);   // wave-uniform: f16-zero region
            const float k2  = s_gw[100 + ii].x;
            const float w2m = s_gw[100 + ii].y * ((ii == 0) ? 1.0f : 2.0f);
            const float cM  = cM0 * w2m;
            const float s   = k1sq + k2 * k2;
            const float rs  = __builtin_amdgcn_rsqf(s);
            const float sqs = s * rs;
            const float k2sc = (k2 * rk1) * k2 * (rs * rs * rs);

            if (!zeroRow) {
                #pragma unroll
                for (int k = 0; k < 11; ++k) {
                    float pws;
                    if (cheapRow || k == 10)    // jj>=80 or row>=80: far-field path
                        pws = phi_pair_cheap(k1sq, L2, s, gr[k]);
                    else
                        pws = phi_pair_pk(k1, k1sq, n2k1, Ttk1, L2, s, sqs, k2sc, gr[k]);
                    float val = pws * (cM * w3r[k]);
                    f1 += val;
                    s_phiT[il * SP + ((k ^ (il & 7)) << 3) + jb] = (_Float16)val;
                }
                // jj 88..95 (granule 11): exact zero
                s_phiT[il * SP + ((11 ^ (il & 7)) << 3) + jb] = (_Float16)0.0f;
            } else {
                #pragma unroll
                for (int k = 0; k < 12; ++k)
                    s_phiT[il * SP + ((k ^ (il & 7)) << 3) + jb] = (_Float16)0.0f;
            }
        }
        __syncthreads();   // B1: phiT ready

        // ---- stage 1 (MFMA): TcT[z][ii] = sum_jj phiT[ii][jj]*B3T[z][jj], K=96 ----
        {
            const int mt  = w & 1;
            const int nt0 = (w >> 1) << 1;
            f32x4 acc1a = {0.f,0.f,0.f,0.f}, acc1b = {0.f,0.f,0.f,0.f};
            const int arow  = mt * 16 + n16;
            const int brow0 = nt0 * 16 + n16;
            const int brow1 = brow0 + 16;
            #pragma unroll
            for (int ks = 0; ks < 3; ++ks) {
                int kg = ks * 4 + quad;
                half8 af  = *(const half8*)&s_phiT[arow  * SP + ((kg ^ (arow  & 7)) << 3)];
                half8 bf0 = *(const half8*)&s_B3T [brow0 * SP + ((kg ^ (brow0 & 7)) << 3)];
                half8 bf1 = *(const half8*)&s_B3T [brow1 * SP + ((kg ^ (brow1 & 7)) << 3)];
                acc1a = __builtin_amdgcn_mfma_f32_16x16x32_f16(af, bf0, acc1a, 0, 0, 0);
                acc1b = __builtin_amdgcn_mfma_f32_16x16x32_f16(af, bf1, acc1b, 0, 0, 0);
            }
            const int ii0 = mt * 16 + quad * 4;
            const int gg  = ii0 >> 3;
            const int wi  = ii0 & 7;
            {
                int z = brow0;
                half4 hv; hv.x=(_Float16)acc1a.x; hv.y=(_Float16)acc1a.y;
                hv.z=(_Float16)acc1a.z; hv.w=(_Float16)acc1a.w;
                *(half4*)&s_TcT[z * ST + ((gg ^ (z & 7)) << 3) + wi] = hv;
            }
            {
                int z = brow1;
                half4 hv; hv.x=(_Float16)acc1b.x; hv.y=(_Float16)acc1b.y;
                hv.z=(_Float16)acc1b.z; hv.w=(_Float16)acc1b.w;
                *(half4*)&s_TcT[z * ST + ((gg ^ (z & 7)) << 3) + wi] = hv;
            }
        }
        __syncthreads();   // B2: TcT ready

        // ---- stage 2 (MFMA): out[y][z] += A2[y][ii]*TcT[z][ii], K=32/chunk ----
        {
            const int yrow = w * 16 + n16;
            const int G = c * 4 + quad;
            half8 a2f = *(const half8*)&s_A2[yrow * SA + ((G ^ (yrow & 7)) << 3)];
            #pragma unroll
            for (int nt = 0; nt < 4; ++nt) {
                int z = nt * 16 + n16;
                half8 bf = *(const half8*)&s_TcT[z * ST + ((quad ^ (z & 7)) << 3)];
                acc2[nt] = __builtin_amdgcn_mfma_f32_16x16x32_f16(a2f, bf, acc2[nt], 0, 0, 0);
            }
        }
        __syncthreads();   // phiT/TcT reused next chunk
    }

    // ---- F1 block reduction -> 1/|F1| ----
    float v = f1;
    #pragma unroll
    for (int off = 32; off > 0; off >>= 1) v += __shfl_down(v, off, 64);
    if (lane == 0) s_red[w] = v;
    __syncthreads();
    if (t == 0) s_red[4] = 1.0f / fabsf(s_red[0] + s_red[1] + s_red[2] + s_red[3]);
    __syncthreads();
    const float rden = s_red[4];

    // ---- epilogue: D2 C-layout -> out[a][y][z] ----
    float* op = out + ((size_t)a << 12);
    #pragma unroll
    for (int nt = 0; nt < 4; ++nt) {
        int z = nt * 16 + n16;
        #pragma unroll
        for (int r = 0; r < 4; ++r) {
            int y = w * 16 + quad * 4 + r;
            op[y * 64 + z] = acc2[nt][r] * rden;
        }
    }
}

extern "C" void kernel_launch(void* const* d_in, const int* in_sizes, int n_in,
                              void* d_out, int out_size, void* d_ws, size_t ws_size,
                              hipStream_t stream) {
    const float* k1 = (const float*)d_in[0];
    const float* dy = (const float*)d_in[1];
    const float* dz = (const float*)d_in[2];
    const float* lL = (const float*)d_in[3];
    const float* lT = (const float*)d_in[4];
    const float* lM = (const float*)d_in[5];
    float* outp = (float*)d_out;
    hipLaunchKernelGGL(spectral_kernel, dim3(512), dim3(BLOCK), 0, stream,
                       k1, dy, dz, lL, lT, lM, outp);
}

// Round 11
// 79.353 us; speedup vs baseline: 1.2252x; 1.0026x over previous
//
#include <hip/hip_runtime.h>
#include <math.h>

#define BLOCK 256
#define LOG2_10 3.3219280948873623f
#define PI_F 3.14159265358979f
#define INV2PI 0.15915494309189535f
#define PW_SCALE 256.0f   // lifts Pw out of f16-subnormal range; cancels in out = num/F1

// LDS row strides in f16 elements
#define SP 128   // phiT / B3T rows; granules 0..11 used (K=96)
#define SA 128   // A2 rows

typedef _Float16 half8 __attribute__((ext_vector_type(8)));
typedef _Float16 half2v __attribute__((ext_vector_type(2)));
typedef float f32x4 __attribute__((ext_vector_type(4)));
typedef float v2f  __attribute__((ext_vector_type(2)));
typedef int   i32x4 __attribute__((ext_vector_type(4)));

__device__ __forceinline__ v2f v2(float a, float b) { v2f r; r.x = a; r.y = b; return r; }

__device__ __forceinline__ float fast_cos(float x_rev) {
    return __builtin_amdgcn_cosf(__builtin_amdgcn_fractf(x_rev));
}

// packed atan2 for y >= 0 (y shared by both elements); result in [0, pi]
__device__ __forceinline__ v2f atan2_pos_pk(float yv, v2f x) {
    float ax0 = __builtin_fabsf(x.x), ax1 = __builtin_fabsf(x.y);
    float mn0 = fminf(ax0, yv), mx0 = fmaxf(ax0, yv);
    float mn1 = fminf(ax1, yv), mx1 = fmaxf(ax1, yv);
    v2f a = v2(mn0 * __builtin_amdgcn_rcpf(mx0), mn1 * __builtin_amdgcn_rcpf(mx1));
    v2f t = a * a;
    v2f p = ((((( -0.0117212f * t + 0.05265332f) * t - 0.11643287f) * t
              + 0.19354346f) * t - 0.33262347f) * t + 0.99997726f) * a;
    float p0 = (yv > ax0) ? (1.57079632679f - p.x) : p.x;
    float p1 = (yv > ax1) ? (1.57079632679f - p.y) : p.y;
    p0 = (x.x < 0.0f) ? (3.14159265359f - p0) : p0;
    p1 = (x.y < 0.0f) ? (3.14159265359f - p1) : p1;
    return v2(p0, p1);
}

// mirror-pair Phi11 (k3 = -g, +g); a/b sides packed as float2 lanes.
// E0*rcp(kk0)^2 = L4*(1+u)^(-17/6), L4 folded into caller's constant.
__device__ __forceinline__ float phi_pair_pk(float k1, float k1sq, float n2k1, float Ttk1,
                                             float L2, float s, float sqs, float k2sc, float g) {
    const float kk  = g * g + s;
    const float bk1 = Ttk1 * __builtin_amdgcn_exp2f((-1.0f/3.0f) * __builtin_amdgcn_logf(L2 * kk));
    const float Qh  = bk1 * g;
    const float sg  = 2.0f * s - kk;                    // s - g^2
    const float cc  = (bk1 * k1) * __builtin_amdgcn_rcpf(kk * s);
    const float yv  = bk1 * sqs;
    const float R   = bk1 * bk1 + kk;                   // s + bk1^2 + g^2
    const v2f x   = v2(kk - Qh, kk + Qh);
    const v2f C1  = cc * v2(sg + Qh, sg - Qh);
    const v2f kk0 = v2(R - 2.0f * Qh, R + 2.0f * Qh);
    const v2f th  = atan2_pos_pk(yv, x);
    const v2f vv  = L2 * kk0 + 1.0f;                    // 1 + u
    const v2f p   = v2(__builtin_amdgcn_exp2f((-17.0f/6.0f) * __builtin_amdgcn_logf(vv.x)),
                       __builtin_amdgcn_exp2f((-17.0f/6.0f) * __builtin_amdgcn_logf(vv.y)));
    const v2f z   = C1 - k2sc * (kk0 * th);
    const v2f k30 = v2(bk1 - g, bk1 + g);
    const v2f qq  = (s * z + n2k1 * k30) * z + (kk0 - k1sq);
    const v2f r   = p * qq;
    return r.x + r.y;
}

// far-field (beta->0) pair: mirror-sum cancels first-order beta; valid when max(ii,jj) >= 72
__device__ __forceinline__ float phi_pair_cheap(float k1sq, float L2, float s, float g) {
    const float kk = g * g + s;
    const float p  = __builtin_amdgcn_exp2f((-17.0f/6.0f) *
                     __builtin_amdgcn_logf(fmaf(L2, kk, 1.0f)));
    return 2.0f * p * (kk - k1sq);
}

__global__ __launch_bounds__(BLOCK, 2)
void spectral_kernel(const float* __restrict__ k1_in,
                     const float* __restrict__ dy_in,
                     const float* __restrict__ dz_in,
                     const float* __restrict__ plogL,
                     const float* __restrict__ plogT,
                     const float* __restrict__ plogM,
                     float* __restrict__ out)
{
    __shared__ __attribute__((aligned(16))) _Float16 s_phiT[2 * 32 * SP]; // double-buffered A1
    __shared__ __attribute__((aligned(16))) _Float16 s_B3T[64 * SP];      // B1: [z][jj]
    __shared__ __attribute__((aligned(16))) _Float16 s_A2[64 * SA];       // A2: [y][ii]
    __shared__ float  s_grid[204];
    __shared__ float2 s_gw[204];     // {grid[j], trapz_w[j]}
    __shared__ float  s_dy[64], s_dz[64];
    __shared__ float  s_red[8];

    const int t    = threadIdx.x;
    const int a    = blockIdx.x;
    const int lane = t & 63;
    const int w    = t >> 6;       // wave id 0..3 (owns z-block w)
    const int n16  = lane & 15;
    const int quad = lane >> 4;

    const float L  = expf(plogL[0]);
    const float Tt = expf(plogT[0]);
    const float M  = expf(plogM[0]);
    const float L2 = L * L;
    const float L4 = L2 * L2;
    const float k1   = k1_in[a];
    const float k1sq = k1 * k1;
    const float n2k1 = -2.0f * k1;
    const float Ttk1 = Tt * k1;
    const float rk1  = __builtin_amdgcn_rcpf(k1);
    const float cM0  = (M * 0.25f / PI_F) * PW_SCALE * L4;

    // ---- grid ----
    if (t < 204) {
        int tt = min(t, 200);
        float v;
        if (tt < 100)       v = -exp2f(LOG2_10 * (-4.0f + 8.0f * (float)(99 - tt) * (1.0f/99.0f)));
        else if (tt == 100) v = 0.0f;
        else                v =  exp2f(LOG2_10 * (-4.0f + 8.0f * (float)(tt - 101) * (1.0f/99.0f)));
        s_grid[t] = v;
    }
    if (t < 64) { s_dy[t] = dy_in[t]; s_dz[t] = dz_in[t]; }
    __syncthreads();

    // ---- trapz weights packed with grid ----
    if (t < 204) {
        float wv = 0.0f;
        if (t == 0)          wv = 0.5f * (s_grid[1] - s_grid[0]);
        else if (t < 200)    wv = 0.5f * (s_grid[t+1] - s_grid[t-1]);
        else if (t == 200)   wv = 0.5f * (s_grid[200] - s_grid[199]);
        s_gw[t] = make_float2(s_grid[t], wv);
    }
    // ---- B3T[z][jj] = cos(grid[100+jj]*dz[z]) f16, zero-pad jj>100 ----
    {
        const int jjp = lane;            // pair index; jj = 2*jjp, 2*jjp+1
        const int jj0 = 2 * jjp, jj1 = jj0 + 1;
        const float g0 = s_grid[min(100 + jj0, 203)];
        const float g1 = s_grid[min(100 + jj1, 203)];
        const int jjg  = jjp >> 2;
        for (int m = 0; m < 16; ++m) {
            int z = w + 4 * m;
            float dzr = s_dz[z] * INV2PI;
            float c0 = (jj0 <= 100) ? fast_cos(g0 * dzr) : 0.0f;
            float c1 = (jj1 <= 100) ? fast_cos(g1 * dzr) : 0.0f;
            half2v pr; pr.x = (_Float16)c0; pr.y = (_Float16)c1;
            *(half2v*)&s_B3T[z * SP + ((jjg ^ (z & 7)) << 3) + (jj0 & 7)] = pr;
        }
    }
    // ---- A2[y][ii] = cos(grid2[ii]*dy[y]) f16, zero-pad ii>100 ----
    {
        float dyr = s_dy[lane] * INV2PI;
        for (int k = 0; k < 16; ++k) {
            int iip = w + 4 * k;
            int i0 = 2 * iip, i1 = i0 + 1;
            float c0 = (i0 <= 100) ? fast_cos(s_grid[min(100 + i0, 203)] * dyr) : 0.0f;
            float c1 = (i1 <= 100) ? fast_cos(s_grid[min(100 + i1, 203)] * dyr) : 0.0f;
            half2v pr; pr.x = (_Float16)c0; pr.y = (_Float16)c1;
            int off = lane * SA + (((iip >> 2) ^ (lane & 7)) << 3) + ((iip & 3) << 1);
            *(half2v*)&s_A2[off] = pr;
        }
    }
    __syncthreads();

    float f1 = 0.0f;
    f32x4 acc2[4];
    #pragma unroll
    for (int i = 0; i < 4; ++i) acc2[i] = (f32x4){0.f, 0.f, 0.f, 0.f};

    const int il = t >> 3;        // structured phase-A row 0..31
    const int jb = t & 7;

    // hoisted jj-grid values, k 0..10 -> jj 0..87
    float gr[11], w3r[11];
    #pragma unroll
    for (int k = 0; k < 11; ++k) {
        const int jj = jb + (k << 3);
        const float2 gwv = s_gw[100 + jj];
        gr[k]  = gwv.x;
        w3r[k] = (jj == 0) ? 0.5f * gwv.y : gwv.y;
    }

    // ======== phase A chunk 0 (structured, rows ii=0..31) into buf 0 ========
    #pragma unroll 1
    for (int c0 = 0; c0 < 1; ++c0) { }  // (no-op; keeps structure readable)
    {
        const int ii = il;
        const float k2  = s_gw[100 + ii].x;
        const float w2m = s_gw[100 + ii].y * ((ii == 0) ? 1.0f : 2.0f);
        const float cM  = cM0 * w2m;
        const float s   = k1sq + k2 * k2;
        const float rs  = __builtin_amdgcn_rsqf(s);
        const float sqs = s * rs;
        const float k2sc = (k2 * rk1) * k2 * (rs * rs * rs);
        _Float16* bp = s_phiT;
        #pragma unroll
        for (int k = 0; k < 9; ++k) {         // jj 0..71: full
            float val = phi_pair_pk(k1, k1sq, n2k1, Ttk1, L2, s, sqs, k2sc, gr[k]) * (cM * w3r[k]);
            f1 += val;
            bp[il * SP + ((k ^ (il & 7)) << 3) + jb] = (_Float16)val;
        }
        #pragma unroll
        for (int k = 9; k < 11; ++k) {        // jj 72..87: cheap
            float val = phi_pair_cheap(k1sq, L2, s, gr[k]) * (cM * w3r[k]);
            f1 += val;
            bp[il * SP + ((k ^ (il & 7)) << 3) + jb] = (_Float16)val;
        }
        bp[il * SP + ((11 ^ (il & 7)) << 3) + jb] = (_Float16)0.0f;   // jj 88..95 zero
    }
    __syncthreads();

    for (int c = 0; c < 3; ++c) {
        const _Float16* rp = s_phiT + (c & 1) * (32 * SP);

        // ---- stage 1 (MFMA, wave-local z-block w): TcT[ii 0..31][z-block w], K=96 ----
        f32x4 acc1[2];
        acc1[0] = (f32x4){0.f,0.f,0.f,0.f};
        acc1[1] = (f32x4){0.f,0.f,0.f,0.f};
        {
            const int arow0 = n16;
            const int arow1 = 16 + n16;
            const int brow  = w * 16 + n16;
            #pragma unroll
            for (int ks = 0; ks < 3; ++ks) {
                int kg = ks * 4 + quad;
                half8 af0 = *(const half8*)&rp[arow0 * SP + ((kg ^ (arow0 & 7)) << 3)];
                half8 af1 = *(const half8*)&rp[arow1 * SP + ((kg ^ (arow1 & 7)) << 3)];
                half8 bf  = *(const half8*)&s_B3T[brow * SP + ((kg ^ (brow & 7)) << 3)];
                acc1[0] = __builtin_amdgcn_mfma_f32_16x16x32_f16(af0, bf, acc1[0], 0, 0, 0);
                acc1[1] = __builtin_amdgcn_mfma_f32_16x16x32_f16(af1, bf, acc1[1], 0, 0, 0);
            }
        }

        // ---- in-wave C->B transpose: bf2[j] = TcT[ii=quad*8+j][z=w*16+n16] ----
        half8 bf2;
        {
            half2v hA0; hA0.x = (_Float16)acc1[0].x; hA0.y = (_Float16)acc1[0].y;
            half2v hA1; hA1.x = (_Float16)acc1[0].z; hA1.y = (_Float16)acc1[0].w;
            half2v hB0; hB0.x = (_Float16)acc1[1].x; hB0.y = (_Float16)acc1[1].y;
            half2v hB1; hB1.x = (_Float16)acc1[1].z; hB1.y = (_Float16)acc1[1].w;
            int pkA0 = __builtin_bit_cast(int, hA0);
            int pkA1 = __builtin_bit_cast(int, hA1);
            int pkB0 = __builtin_bit_cast(int, hB0);
            int pkB1 = __builtin_bit_cast(int, hB1);
            const int addr_a = (((quad & 1) << 5) + n16) << 2;   // src lane 2(q&1)*16+n16, bytes
            const int addr_b = addr_a + 64;                      // src lane +16
            int a0 = __builtin_amdgcn_ds_bpermute(addr_a, pkA0);
            int b0 = __builtin_amdgcn_ds_bpermute(addr_a, pkB0);
            int a1 = __builtin_amdgcn_ds_bpermute(addr_a, pkA1);
            int b1 = __builtin_amdgcn_ds_bpermute(addr_a, pkB1);
            int a2 = __builtin_amdgcn_ds_bpermute(addr_b, pkA0);
            int b2 = __builtin_amdgcn_ds_bpermute(addr_b, pkB0);
            int a3 = __builtin_amdgcn_ds_bpermute(addr_b, pkA1);
            int b3 = __builtin_amdgcn_ds_bpermute(addr_b, pkB1);
            const bool lo = (quad < 2);                          // dest ii-tile select
            i32x4 wv;
            wv.x = lo ? a0 : b0;
            wv.y = lo ? a1 : b1;
            wv.z = lo ? a2 : b2;
            wv.w = lo ? a3 : b3;
            bf2 = __builtin_bit_cast(half8, wv);
        }

        // ---- stage 2 (MFMA): out[y-blocks][z-block w] += A2 * bf2, K=32 ----
        {
            const int G = c * 4 + quad;
            #pragma unroll
            for (int yb = 0; yb < 4; ++yb) {
                int yrow = yb * 16 + n16;
                half8 a2f = *(const half8*)&s_A2[yrow * SA + ((G ^ (yrow & 7)) << 3)];
                acc2[yb] = __builtin_amdgcn_mfma_f32_16x16x32_f16(a2f, bf2, acc2[yb], 0, 0, 0);
            }
        }

        // ---- produce next chunk's phiT (other buffer) ----
        if (c == 0) {
            // chunk 1 structured: rows ii = 32..63 (all full region)
            const int ii = 32 + il;
            const float k2  = s_gw[100 + ii].x;
            const float cM  = cM0 * (s_gw[100 + ii].y * 2.0f);
            const float s   = k1sq + k2 * k2;
            const float rs  = __builtin_amdgcn_rsqf(s);
            const float sqs = s * rs;
            const float k2sc = (k2 * rk1) * k2 * (rs * rs * rs);
            _Float16* bp = s_phiT + 32 * SP;
            #pragma unroll
            for (int k = 0; k < 9; ++k) {
                float val = phi_pair_pk(k1, k1sq, n2k1, Ttk1, L2, s, sqs, k2sc, gr[k]) * (cM * w3r[k]);
                f1 += val;
                bp[il * SP + ((k ^ (il & 7)) << 3) + jb] = (_Float16)val;
            }
            #pragma unroll
            for (int k = 9; k < 11; ++k) {
                float val = phi_pair_cheap(k1sq, L2, s, gr[k]) * (cM * w3r[k]);
                f1 += val;
                bp[il * SP + ((k ^ (il & 7)) << 3) + jb] = (_Float16)val;
            }
            bp[il * SP + ((11 ^ (il & 7)) << 3) + jb] = (_Float16)0.0f;
        } else if (c == 1) {
            // chunk 2 (rows ii = 64..95) flattened & balanced into buf 0
            _Float16* bp = s_phiT;
            // zeros: rows 24..31 all 12 granules + rows 0..23 granule 11 -> 120 half8
            if (t < 120) {
                int row, slot;
                if (t < 96) { row = 24 + t / 12; int g = t - (row - 24) * 12; slot = g ^ (row & 7); }
                else        { row = t - 96;      slot = 11 ^ (row & 7); }
                half8 zz = {};
                *(half8*)&bp[row * SP + (slot << 3)] = zz;
            }
            // full cells: ii 64..71 x jj 0..71 = 576
            #pragma unroll
            for (int m = 0; m < 3; ++m) {
                int e = t + 256 * m;
                if (e < 576) {
                    int r8 = e / 72;
                    int jj = e - r8 * 72;
                    int ii = 64 + r8;
                    float k2  = s_gw[100 + ii].x;
                    float cM  = cM0 * (s_gw[100 + ii].y * 2.0f);
                    float s   = k1sq + k2 * k2;
                    float rs  = __builtin_amdgcn_rsqf(s);
                    float sqs = s * rs;
                    float k2sc = (k2 * rk1) * k2 * (rs * rs * rs);
                    float2 gwv = s_gw[100 + jj];
                    float w3s = (jj == 0) ? 0.5f * gwv.y : gwv.y;
                    float val = phi_pair_pk(k1, k1sq, n2k1, Ttk1, L2, s, sqs, k2sc, gwv.x) * cM * w3s;
                    f1 += val;
                    bp[r8 * SP + (((jj >> 3) ^ (r8 & 7)) << 3) + (jj & 7)] = (_Float16)val;
                }
            }
            // cheap cells: (ii 64..71 x jj 72..87) + (ii 72..87 x jj 0..87) = 1536 = 6/thread
            #pragma unroll
            for (int m = 0; m < 6; ++m) {
                int e = t + 256 * m;
                int ii, jj;
                if (e < 128) { ii = 64 + (e >> 4); jj = 72 + (e & 15); }
                else { int e2 = e - 128; int r16 = e2 / 88; jj = e2 - r16 * 88; ii = 72 + r16; }
                float k2 = s_gw[100 + ii].x;
                float cM = cM0 * (s_gw[100 + ii].y * 2.0f);
                float s  = k1sq + k2 * k2;
                float2 gwv = s_gw[100 + jj];
                float w3s = (jj == 0) ? 0.5f * gwv.y : gwv.y;
                float val = phi_pair_cheap(k1sq, L2, s, gwv.x) * cM * w3s;
                f1 += val;
                int row = ii - 64;
                bp[row * SP + (((jj >> 3) ^ (row & 7)) << 3) + (jj & 7)] = (_Float16)val;
            }
        }
        __syncthreads();
    }

    // ---- F1 block reduction -> 1/|F1| ----
    float v = f1;
    #pragma unroll
    for (int off = 32; off > 0; off >>= 1) v += __shfl_down(v, off, 64);
    if (lane == 0) s_red[w] = v;
    __syncthreads();
    if (t == 0) s_red[4] = 1.0f / fabsf(s_red[0] + s_red[1] + s_red[2] + s_red[3]);
    __syncthreads();
    const float rden = s_red[4];

    // ---- epilogue: acc2[yb][r] = out[y = yb*16+quad*4+r][z = w*16+n16] ----
    float* op = out + ((size_t)a << 12) + (w * 16 + n16);
    #pragma unroll
    for (int yb = 0; yb < 4; ++yb) {
        #pragma unroll
        for (int r = 0; r < 4; ++r) {
            int y = yb * 16 + quad * 4 + r;
            op[y * 64] = acc2[yb][r] * rden;
        }
    }
}

extern "C" void kernel_launch(void* const* d_in, const int* in_sizes, int n_in,
                              void* d_out, int out_size, void* d_ws, size_t ws_size,
                              hipStream_t stream) {
    const float* k1 = (const float*)d_in[0];
    const float* dy = (const float*)d_in[1];
    const float* dz = (const float*)d_in[2];
    const float* lL = (const float*)d_in[3];
    const float* lT = (const float*)d_in[4];
    const float* lM = (const float*)d_in[5];
    float* outp = (float*)d_out;
    hipLaunchKernelGGL(spectral_kernel, dim3(512), dim3(BLOCK), 0, stream,
                       k1, dy, dz, lL, lT, lM, outp);
}

// Round 12
// 79.114 us; speedup vs baseline: 1.2289x; 1.0030x over previous
//
#include <hip/hip_runtime.h>
#include <math.h>

#define BLOCK 256
#define LOG2_10 3.3219280948873623f
#define PI_F 3.14159265358979f
#define INV2PI 0.15915494309189535f
#define PW_SCALE 256.0f   // lifts Pw out of f16-subnormal range; cancels in out = num/F1

// LDS row strides in f16 elements
#define SP 128   // phiT / B3T rows; granules 0..11 used (K=96)
#define SA 128   // A2 rows
#define FT 56    // full-eval threshold: cells with max(ii,jj) < FT use the exact path

typedef _Float16 half8 __attribute__((ext_vector_type(8)));
typedef _Float16 half2v __attribute__((ext_vector_type(2)));
typedef float f32x4 __attribute__((ext_vector_type(4)));
typedef float v2f  __attribute__((ext_vector_type(2)));
typedef int   i32x4 __attribute__((ext_vector_type(4)));

__device__ __forceinline__ v2f v2(float a, float b) { v2f r; r.x = a; r.y = b; return r; }

__device__ __forceinline__ float fast_cos(float x_rev) {
    return __builtin_amdgcn_cosf(__builtin_amdgcn_fractf(x_rev));
}

// packed atan2 for y >= 0 (y shared by both elements); result in [0, pi]
__device__ __forceinline__ v2f atan2_pos_pk(float yv, v2f x) {
    float ax0 = __builtin_fabsf(x.x), ax1 = __builtin_fabsf(x.y);
    float mn0 = fminf(ax0, yv), mx0 = fmaxf(ax0, yv);
    float mn1 = fminf(ax1, yv), mx1 = fmaxf(ax1, yv);
    v2f a = v2(mn0 * __builtin_amdgcn_rcpf(mx0), mn1 * __builtin_amdgcn_rcpf(mx1));
    v2f t = a * a;
    v2f p = ((((( -0.0117212f * t + 0.05265332f) * t - 0.11643287f) * t
              + 0.19354346f) * t - 0.33262347f) * t + 0.99997726f) * a;
    float p0 = (yv > ax0) ? (1.57079632679f - p.x) : p.x;
    float p1 = (yv > ax1) ? (1.57079632679f - p.y) : p.y;
    p0 = (x.x < 0.0f) ? (3.14159265359f - p0) : p0;
    p1 = (x.y < 0.0f) ? (3.14159265359f - p1) : p1;
    return v2(p0, p1);
}

// mirror-pair Phi11 (k3 = -g, +g); a/b sides packed as float2 lanes.
__device__ __forceinline__ float phi_pair_pk(float k1, float k1sq, float n2k1, float Ttk1,
                                             float L2, float s, float sqs, float k2sc, float g) {
    const float kk  = g * g + s;
    const float bk1 = Ttk1 * __builtin_amdgcn_exp2f((-1.0f/3.0f) * __builtin_amdgcn_logf(L2 * kk));
    const float Qh  = bk1 * g;
    const float sg  = 2.0f * s - kk;                    // s - g^2
    const float cc  = (bk1 * k1) * __builtin_amdgcn_rcpf(kk * s);
    const float yv  = bk1 * sqs;
    const float R   = bk1 * bk1 + kk;                   // s + bk1^2 + g^2
    const v2f x   = v2(kk - Qh, kk + Qh);
    const v2f C1  = cc * v2(sg + Qh, sg - Qh);
    const v2f kk0 = v2(R - 2.0f * Qh, R + 2.0f * Qh);
    const v2f th  = atan2_pos_pk(yv, x);
    const v2f vv  = L2 * kk0 + 1.0f;                    // 1 + u
    const v2f p   = v2(__builtin_amdgcn_exp2f((-17.0f/6.0f) * __builtin_amdgcn_logf(vv.x)),
                       __builtin_amdgcn_exp2f((-17.0f/6.0f) * __builtin_amdgcn_logf(vv.y)));
    const v2f z   = C1 - k2sc * (kk0 * th);
    const v2f k30 = v2(bk1 - g, bk1 + g);
    const v2f qq  = (s * z + n2k1 * k30) * z + (kk0 - k1sq);
    const v2f r   = p * qq;
    return r.x + r.y;
}

// far-field (beta->0) pair: mirror-sum cancels first-order beta; valid when max(ii,jj) >= FT
__device__ __forceinline__ float phi_pair_cheap(float k1sq, float L2, float s, float g) {
    const float kk = g * g + s;
    const float p  = __builtin_amdgcn_exp2f((-17.0f/6.0f) *
                     __builtin_amdgcn_logf(fmaf(L2, kk, 1.0f)));
    return 2.0f * p * (kk - k1sq);
}

__global__ __launch_bounds__(BLOCK, 2)
void spectral_kernel(const float* __restrict__ k1_in,
                     const float* __restrict__ dy_in,
                     const float* __restrict__ dz_in,
                     const float* __restrict__ plogL,
                     const float* __restrict__ plogT,
                     const float* __restrict__ plogM,
                     float* __restrict__ out)
{
    __shared__ __attribute__((aligned(16))) _Float16 s_phiT[2 * 32 * SP]; // double-buffered A1
    __shared__ __attribute__((aligned(16))) _Float16 s_B3T[64 * SP];      // B1: [z][jj]
    __shared__ __attribute__((aligned(16))) _Float16 s_A2[64 * SA];       // A2: [y][ii]
    __shared__ float  s_grid[204];
    __shared__ float2 s_gw[204];     // {grid[j], trapz_w[j]}
    __shared__ float  s_dy[64], s_dz[64];
    __shared__ float  s_red[8];

    const int t    = threadIdx.x;
    const int a    = blockIdx.x;
    const int lane = t & 63;
    const int w    = t >> 6;       // wave id 0..3 (owns z-block w)
    const int n16  = lane & 15;
    const int quad = lane >> 4;

    const float L  = expf(plogL[0]);
    const float Tt = expf(plogT[0]);
    const float M  = expf(plogM[0]);
    const float L2 = L * L;
    const float L4 = L2 * L2;
    const float k1   = k1_in[a];
    const float k1sq = k1 * k1;
    const float n2k1 = -2.0f * k1;
    const float Ttk1 = Tt * k1;
    const float rk1  = __builtin_amdgcn_rcpf(k1);
    const float cM0  = (M * 0.25f / PI_F) * PW_SCALE * L4;

    // ---- grid ----
    if (t < 204) {
        int tt = min(t, 200);
        float v;
        if (tt < 100)       v = -exp2f(LOG2_10 * (-4.0f + 8.0f * (float)(99 - tt) * (1.0f/99.0f)));
        else if (tt == 100) v = 0.0f;
        else                v =  exp2f(LOG2_10 * (-4.0f + 8.0f * (float)(tt - 101) * (1.0f/99.0f)));
        s_grid[t] = v;
    }
    if (t < 64) { s_dy[t] = dy_in[t]; s_dz[t] = dz_in[t]; }
    __syncthreads();

    // ---- trapz weights packed with grid ----
    if (t < 204) {
        float wv = 0.0f;
        if (t == 0)          wv = 0.5f * (s_grid[1] - s_grid[0]);
        else if (t < 200)    wv = 0.5f * (s_grid[t+1] - s_grid[t-1]);
        else if (t == 200)   wv = 0.5f * (s_grid[200] - s_grid[199]);
        s_gw[t] = make_float2(s_grid[t], wv);
    }
    // ---- B3T[z][jj] = cos(grid[100+jj]*dz[z]) f16, jj < 96 only (granules 0..11) ----
    {
        const int jjp = lane;            // pair index; jj = 2*jjp, 2*jjp+1
        const int jj0 = 2 * jjp, jj1 = jj0 + 1;
        if (jj0 < 96) {
            const float g0 = s_grid[100 + jj0];
            const float g1 = s_grid[100 + jj1];
            const int jjg  = jjp >> 2;
            for (int m = 0; m < 16; ++m) {
                int z = w + 4 * m;
                float dzr = s_dz[z] * INV2PI;
                float c0 = (jj0 < 88) ? fast_cos(g0 * dzr) : 0.0f;   // jj>=88 is f16-zero region
                float c1 = (jj1 < 88) ? fast_cos(g1 * dzr) : 0.0f;
                half2v pr; pr.x = (_Float16)c0; pr.y = (_Float16)c1;
                *(half2v*)&s_B3T[z * SP + ((jjg ^ (z & 7)) << 3) + (jj0 & 7)] = pr;
            }
        }
    }
    // ---- A2[y][ii] = cos(grid2[ii]*dy[y]) f16, ii < 96 only ----
    {
        float dyr = s_dy[lane] * INV2PI;
        for (int k = 0; k < 12; ++k) {
            int iip = w + 4 * k;               // pair index 0..47 -> ii 0..95
            int i0 = 2 * iip, i1 = i0 + 1;
            float c0 = (i0 < 88) ? fast_cos(s_grid[100 + i0] * dyr) : 0.0f;
            float c1 = (i1 < 88) ? fast_cos(s_grid[100 + i1] * dyr) : 0.0f;
            half2v pr; pr.x = (_Float16)c0; pr.y = (_Float16)c1;
            int off = lane * SA + (((iip >> 2) ^ (lane & 7)) << 3) + ((iip & 3) << 1);
            *(half2v*)&s_A2[off] = pr;
        }
    }
    __syncthreads();

    float f1 = 0.0f;
    f32x4 acc2[4];
    #pragma unroll
    for (int i = 0; i < 4; ++i) acc2[i] = (f32x4){0.f, 0.f, 0.f, 0.f};

    // ---- per-cell eval helpers (flat lists; row quantities recomputed per cell) ----
    auto do_full = [&](int ii, int jj, int row, _Float16* bp) {
        float k2  = s_gw[100 + ii].x;
        float cM  = cM0 * (s_gw[100 + ii].y * ((ii == 0) ? 1.0f : 2.0f));
        float s   = k1sq + k2 * k2;
        float rs  = __builtin_amdgcn_rsqf(s);
        float sqs = s * rs;
        float k2sc = (k2 * rk1) * k2 * (rs * rs * rs);
        float2 gwv = s_gw[100 + jj];
        float w3s = (jj == 0) ? 0.5f * gwv.y : gwv.y;
        float val = phi_pair_pk(k1, k1sq, n2k1, Ttk1, L2, s, sqs, k2sc, gwv.x) * cM * w3s;
        f1 += val;
        bp[row * SP + (((jj >> 3) ^ (row & 7)) << 3) + (jj & 7)] = (_Float16)val;
    };
    auto do_cheap = [&](int ii, int jj, int row, _Float16* bp) {
        float k2 = s_gw[100 + ii].x;
        float cM = cM0 * (s_gw[100 + ii].y * ((ii == 0) ? 1.0f : 2.0f));
        float s  = k1sq + k2 * k2;
        float2 gwv = s_gw[100 + jj];
        float w3s = (jj == 0) ? 0.5f * gwv.y : gwv.y;
        float val = phi_pair_cheap(k1sq, L2, s, gwv.x) * cM * w3s;
        f1 += val;
        bp[row * SP + (((jj >> 3) ^ (row & 7)) << 3) + (jj & 7)] = (_Float16)val;
    };

    // ======== produce chunk 0 (ii 0..31) into buf 0 ========
    {
        _Float16* bp = s_phiT;
        if (t < 32) {     // granule 11 (jj 88..95) zero
            half8 zz = {};
            *(half8*)&bp[t * SP + ((11 ^ (t & 7)) << 3)] = zz;
        }
        // full: ii 0..31 x jj 0..55 = 1792 = 7/thread
        #pragma unroll 2
        for (int m = 0; m < 7; ++m) {
            int e = t + 256 * m;
            int row = e / FT, jj = e - row * FT;
            do_full(row, jj, row, bp);
        }
        // cheap: ii 0..31 x jj 56..87 = 1024 = 4/thread
        #pragma unroll
        for (int m = 0; m < 4; ++m) {
            int e = t + 256 * m;
            int row = e >> 5, jj = FT + (e & 31);
            do_cheap(row, jj, row, bp);
        }
    }
    __syncthreads();

    for (int c = 0; c < 3; ++c) {
        const _Float16* rp = s_phiT + (c & 1) * (32 * SP);

        // ---- stage 1 (MFMA, wave-local z-block w): TcT[ii 0..31][z-block w], K=96 ----
        f32x4 acc1[2];
        acc1[0] = (f32x4){0.f,0.f,0.f,0.f};
        acc1[1] = (f32x4){0.f,0.f,0.f,0.f};
        {
            const int arow0 = n16;
            const int arow1 = 16 + n16;
            const int brow  = w * 16 + n16;
            #pragma unroll
            for (int ks = 0; ks < 3; ++ks) {
                int kg = ks * 4 + quad;
                half8 af0 = *(const half8*)&rp[arow0 * SP + ((kg ^ (arow0 & 7)) << 3)];
                half8 af1 = *(const half8*)&rp[arow1 * SP + ((kg ^ (arow1 & 7)) << 3)];
                half8 bf  = *(const half8*)&s_B3T[brow * SP + ((kg ^ (brow & 7)) << 3)];
                acc1[0] = __builtin_amdgcn_mfma_f32_16x16x32_f16(af0, bf, acc1[0], 0, 0, 0);
                acc1[1] = __builtin_amdgcn_mfma_f32_16x16x32_f16(af1, bf, acc1[1], 0, 0, 0);
            }
        }

        // ---- in-wave C->B transpose: bf2[j] = TcT[ii=quad*8+j][z=w*16+n16] ----
        half8 bf2;
        {
            half2v hA0; hA0.x = (_Float16)acc1[0].x; hA0.y = (_Float16)acc1[0].y;
            half2v hA1; hA1.x = (_Float16)acc1[0].z; hA1.y = (_Float16)acc1[0].w;
            half2v hB0; hB0.x = (_Float16)acc1[1].x; hB0.y = (_Float16)acc1[1].y;
            half2v hB1; hB1.x = (_Float16)acc1[1].z; hB1.y = (_Float16)acc1[1].w;
            int pkA0 = __builtin_bit_cast(int, hA0);
            int pkA1 = __builtin_bit_cast(int, hA1);
            int pkB0 = __builtin_bit_cast(int, hB0);
            int pkB1 = __builtin_bit_cast(int, hB1);
            const int addr_a = (((quad & 1) << 5) + n16) << 2;   // src lane 2(q&1)*16+n16, bytes
            const int addr_b = addr_a + 64;                      // src lane +16
            int a0 = __builtin_amdgcn_ds_bpermute(addr_a, pkA0);
            int b0 = __builtin_amdgcn_ds_bpermute(addr_a, pkB0);
            int a1 = __builtin_amdgcn_ds_bpermute(addr_a, pkA1);
            int b1 = __builtin_amdgcn_ds_bpermute(addr_a, pkB1);
            int a2 = __builtin_amdgcn_ds_bpermute(addr_b, pkA0);
            int b2 = __builtin_amdgcn_ds_bpermute(addr_b, pkB0);
            int a3 = __builtin_amdgcn_ds_bpermute(addr_b, pkA1);
            int b3 = __builtin_amdgcn_ds_bpermute(addr_b, pkB1);
            const bool lo = (quad < 2);                          // dest ii-tile select
            i32x4 wv;
            wv.x = lo ? a0 : b0;
            wv.y = lo ? a1 : b1;
            wv.z = lo ? a2 : b2;
            wv.w = lo ? a3 : b3;
            bf2 = __builtin_bit_cast(half8, wv);
        }

        // ---- stage 2 (MFMA): out[y-blocks][z-block w] += A2 * bf2, K=32 ----
        {
            const int G = c * 4 + quad;
            #pragma unroll
            for (int yb = 0; yb < 4; ++yb) {
                int yrow = yb * 16 + n16;
                half8 a2f = *(const half8*)&s_A2[yrow * SA + ((G ^ (yrow & 7)) << 3)];
                acc2[yb] = __builtin_amdgcn_mfma_f32_16x16x32_f16(a2f, bf2, acc2[yb], 0, 0, 0);
            }
        }

        // ---- produce next chunk's phiT (other buffer) ----
        if (c == 0) {
            // chunk 1 (ii 32..63) into buf 1
            _Float16* bp = s_phiT + 32 * SP;
            if (t < 32) {     // granule 11 zero
                half8 zz = {};
                *(half8*)&bp[t * SP + ((11 ^ (t & 7)) << 3)] = zz;
            }
            // full: ii 32..55 x jj 0..55 = 1344 (m<6, guard)
            #pragma unroll 2
            for (int m = 0; m < 6; ++m) {
                int e = t + 256 * m;
                if (e < 1344) {
                    int row = e / FT, jj = e - row * FT;
                    do_full(32 + row, jj, row, bp);
                }
            }
            // cheap: (ii 32..55 x jj 56..87 = 768) + (ii 56..63 x jj 0..87 = 704) = 1472
            #pragma unroll
            for (int m = 0; m < 6; ++m) {
                int e = t + 256 * m;
                if (e < 1472) {
                    int row, jj;
                    if (e < 768) { row = e >> 5; jj = FT + (e & 31); }
                    else { int e2 = e - 768; row = 24 + e2 / 88; jj = e2 - (row - 24) * 88; }
                    do_cheap(32 + row, jj, row, bp);
                }
            }
        } else if (c == 1) {
            // chunk 2 (ii 64..95) into buf 0: rows 0..23 cheap, rows 24..31 zero
            _Float16* bp = s_phiT;
            if (t < 120) {    // rows 24..31 all granules (96) + rows 0..23 granule 11 (24)
                int row, slot;
                if (t < 96) { row = 24 + t / 12; int g = t - (row - 24) * 12; slot = g ^ (row & 7); }
                else        { row = t - 96;      slot = 11 ^ (row & 7); }
                half8 zz = {};
                *(half8*)&bp[row * SP + (slot << 3)] = zz;
            }
            // cheap: ii 64..87 x jj 0..87 = 2112 (m<9, guard)
            #pragma unroll
            for (int m = 0; m < 9; ++m) {
                int e = t + 256 * m;
                if (e < 2112) {
                    int row = e / 88, jj = e - row * 88;
                    do_cheap(64 + row, jj, row, bp);
                }
            }
        }
        __syncthreads();
    }

    // ---- F1 block reduction -> 1/|F1| ----
    float v = f1;
    #pragma unroll
    for (int off = 32; off > 0; off >>= 1) v += __shfl_down(v, off, 64);
    if (lane == 0) s_red[w] = v;
    __syncthreads();
    if (t == 0) s_red[4] = 1.0f / fabsf(s_red[0] + s_red[1] + s_red[2] + s_red[3]);
    __syncthreads();
    const float rden = s_red[4];

    // ---- epilogue: acc2[yb][r] = out[y = yb*16+quad*4+r][z = w*16+n16] ----
    float* op = out + ((size_t)a << 12) + (w * 16 + n16);
    #pragma unroll
    for (int yb = 0; yb < 4; ++yb) {
        #pragma unroll
        for (int r = 0; r < 4; ++r) {
            int y = yb * 16 + quad * 4 + r;
            op[y * 64] = acc2[yb][r] * rden;
        }
    }
}

extern "C" void kernel_launch(void* const* d_in, const int* in_sizes, int n_in,
                              void* d_out, int out_size, void* d_ws, size_t ws_size,
                              hipStream_t stream) {
    const float* k1 = (const float*)d_in[0];
    const float* dy = (const float*)d_in[1];
    const float* dz = (const float*)d_in[2];
    const float* lL = (const float*)d_in[3];
    const float* lT = (const float*)d_in[4];
    const float* lM = (const float*)d_in[5];
    float* outp = (float*)d_out;
    hipLaunchKernelGGL(spectral_kernel, dim3(512), dim3(BLOCK), 0, stream,
                       k1, dy, dz, lL, lT, lM, outp);
}

// Round 13
// 75.688 us; speedup vs baseline: 1.2845x; 1.0453x over previous
//
#include <hip/hip_runtime.h>
#include <math.h>

#define BLOCK 512
#define LOG2_10 3.3219280948873623f
#define PI_F 3.14159265358979f
#define INV2PI 0.15915494309189535f
#define PW_SCALE 256.0f   // lifts Pw out of f16-subnormal range; cancels in out = num/F1

// LDS row strides in f16 elements
#define SP 128   // phiT / B3T rows; granules 0..11 used (K=96)
#define SA 128   // A2 rows
#define FT 56    // full-eval threshold: cells with max(ii,jj) < FT use the exact path

typedef _Float16 half8 __attribute__((ext_vector_type(8)));
typedef _Float16 half2v __attribute__((ext_vector_type(2)));
typedef float f32x4 __attribute__((ext_vector_type(4)));
typedef float v2f  __attribute__((ext_vector_type(2)));
typedef int   i32x4 __attribute__((ext_vector_type(4)));

__device__ __forceinline__ v2f v2(float a, float b) { v2f r; r.x = a; r.y = b; return r; }

__device__ __forceinline__ float fast_cos(float x_rev) {
    return __builtin_amdgcn_cosf(__builtin_amdgcn_fractf(x_rev));
}

// packed atan2 for y >= 0 (y shared by both elements); result in [0, pi]
__device__ __forceinline__ v2f atan2_pos_pk(float yv, v2f x) {
    float ax0 = __builtin_fabsf(x.x), ax1 = __builtin_fabsf(x.y);
    float mn0 = fminf(ax0, yv), mx0 = fmaxf(ax0, yv);
    float mn1 = fminf(ax1, yv), mx1 = fmaxf(ax1, yv);
    v2f a = v2(mn0 * __builtin_amdgcn_rcpf(mx0), mn1 * __builtin_amdgcn_rcpf(mx1));
    v2f t = a * a;
    v2f p = ((((( -0.0117212f * t + 0.05265332f) * t - 0.11643287f) * t
              + 0.19354346f) * t - 0.33262347f) * t + 0.99997726f) * a;
    float p0 = (yv > ax0) ? (1.57079632679f - p.x) : p.x;
    float p1 = (yv > ax1) ? (1.57079632679f - p.y) : p.y;
    p0 = (x.x < 0.0f) ? (3.14159265359f - p0) : p0;
    p1 = (x.y < 0.0f) ? (3.14159265359f - p1) : p1;
    return v2(p0, p1);
}

// mirror-pair Phi11 (k3 = -g, +g); a/b sides packed as float2 lanes.
__device__ __forceinline__ float phi_pair_pk(float k1, float k1sq, float n2k1, float Ttk1,
                                             float L2, float s, float sqs, float k2sc, float g) {
    const float kk  = g * g + s;
    const float bk1 = Ttk1 * __builtin_amdgcn_exp2f((-1.0f/3.0f) * __builtin_amdgcn_logf(L2 * kk));
    const float Qh  = bk1 * g;
    const float sg  = 2.0f * s - kk;                    // s - g^2
    const float cc  = (bk1 * k1) * __builtin_amdgcn_rcpf(kk * s);
    const float yv  = bk1 * sqs;
    const float R   = bk1 * bk1 + kk;                   // s + bk1^2 + g^2
    const v2f x   = v2(kk - Qh, kk + Qh);
    const v2f C1  = cc * v2(sg + Qh, sg - Qh);
    const v2f kk0 = v2(R - 2.0f * Qh, R + 2.0f * Qh);
    const v2f th  = atan2_pos_pk(yv, x);
    const v2f vv  = L2 * kk0 + 1.0f;                    // 1 + u
    const v2f p   = v2(__builtin_amdgcn_exp2f((-17.0f/6.0f) * __builtin_amdgcn_logf(vv.x)),
                       __builtin_amdgcn_exp2f((-17.0f/6.0f) * __builtin_amdgcn_logf(vv.y)));
    const v2f z   = C1 - k2sc * (kk0 * th);
    const v2f k30 = v2(bk1 - g, bk1 + g);
    const v2f qq  = (s * z + n2k1 * k30) * z + (kk0 - k1sq);
    const v2f r   = p * qq;
    return r.x + r.y;
}

// far-field (beta->0) pair: mirror-sum cancels first-order beta; valid when max(ii,jj) >= FT
__device__ __forceinline__ float phi_pair_cheap(float k1sq, float L2, float s, float g) {
    const float kk = g * g + s;
    const float p  = __builtin_amdgcn_exp2f((-17.0f/6.0f) *
                     __builtin_amdgcn_logf(fmaf(L2, kk, 1.0f)));
    return 2.0f * p * (kk - k1sq);
}

__global__ __launch_bounds__(BLOCK, 2)
void spectral_kernel(const float* __restrict__ k1_in,
                     const float* __restrict__ dy_in,
                     const float* __restrict__ dz_in,
                     const float* __restrict__ plogL,
                     const float* __restrict__ plogT,
                     const float* __restrict__ plogM,
                     float* __restrict__ out)
{
    // phiT layout: [a][buf][32*SP]
    __shared__ __attribute__((aligned(16))) _Float16 s_phiT[2 * 2 * 32 * SP];
    __shared__ __attribute__((aligned(16))) _Float16 s_B3T[64 * SP];      // B1: [z][jj]
    __shared__ __attribute__((aligned(16))) _Float16 s_A2[64 * SA];       // A2: [y][ii]
    __shared__ float  s_grid[204];
    __shared__ float2 s_gw[204];     // {grid[j], trapz_w[j]}
    __shared__ float  s_dy[64], s_dz[64];
    __shared__ float  s_redA[8], s_redB[8], s_rden[2];

    const int t    = threadIdx.x;
    const int a0   = blockIdx.x * 2;
    const int lane = t & 63;
    const int w    = t >> 6;       // wave id 0..7: ia = w>>2, z-block = w&3
    const int n16  = lane & 15;
    const int quad = lane >> 4;

    const float L  = expf(plogL[0]);
    const float Tt = expf(plogT[0]);
    const float M  = expf(plogM[0]);
    const float L2 = L * L;
    const float L4 = L2 * L2;
    const float k1A   = k1_in[a0];
    const float k1B   = k1_in[a0 + 1];
    const float k1sqA = k1A * k1A,  k1sqB = k1B * k1B;
    const float n2k1A = -2.0f * k1A, n2k1B = -2.0f * k1B;
    const float Ttk1A = Tt * k1A,    Ttk1B = Tt * k1B;
    const float rk1A  = __builtin_amdgcn_rcpf(k1A);
    const float rk1B  = __builtin_amdgcn_rcpf(k1B);
    const float cM0   = (M * 0.25f / PI_F) * PW_SCALE * L4;   // a-independent

    // ---- grid ----
    if (t < 204) {
        int tt = min(t, 200);
        float v;
        if (tt < 100)       v = -exp2f(LOG2_10 * (-4.0f + 8.0f * (float)(99 - tt) * (1.0f/99.0f)));
        else if (tt == 100) v = 0.0f;
        else                v =  exp2f(LOG2_10 * (-4.0f + 8.0f * (float)(tt - 101) * (1.0f/99.0f)));
        s_grid[t] = v;
    }
    if (t < 64) { s_dy[t] = dy_in[t]; s_dz[t] = dz_in[t]; }
    __syncthreads();

    // ---- trapz weights packed with grid ----
    if (t < 204) {
        float wv = 0.0f;
        if (t == 0)          wv = 0.5f * (s_grid[1] - s_grid[0]);
        else if (t < 200)    wv = 0.5f * (s_grid[t+1] - s_grid[t-1]);
        else if (t == 200)   wv = 0.5f * (s_grid[200] - s_grid[199]);
        s_gw[t] = make_float2(s_grid[t], wv);
    }
    // ---- B3T[z][jj] = cos(grid[100+jj]*dz[z]) f16, jj < 96 (8 waves split z) ----
    {
        const int jjp = lane;
        const int jj0 = 2 * jjp, jj1 = jj0 + 1;
        if (jj0 < 96) {
            const float g0 = s_grid[100 + jj0];
            const float g1 = s_grid[100 + jj1];
            const int jjg  = jjp >> 2;
            #pragma unroll
            for (int m = 0; m < 8; ++m) {
                int z = w + 8 * m;
                float dzr = s_dz[z] * INV2PI;
                float c0 = (jj0 < 88) ? fast_cos(g0 * dzr) : 0.0f;
                float c1 = (jj1 < 88) ? fast_cos(g1 * dzr) : 0.0f;
                half2v pr; pr.x = (_Float16)c0; pr.y = (_Float16)c1;
                *(half2v*)&s_B3T[z * SP + ((jjg ^ (z & 7)) << 3) + (jj0 & 7)] = pr;
            }
        }
    }
    // ---- A2[y][ii] = cos(grid2[ii]*dy[y]) f16, ii < 96 ----
    {
        float dyr = s_dy[lane] * INV2PI;
        #pragma unroll
        for (int k = 0; k < 6; ++k) {
            int iip = w + 8 * k;               // 0..47 -> ii 0..95
            int i0 = 2 * iip, i1 = i0 + 1;
            float c0 = (i0 < 88) ? fast_cos(s_grid[100 + i0] * dyr) : 0.0f;
            float c1 = (i1 < 88) ? fast_cos(s_grid[100 + i1] * dyr) : 0.0f;
            half2v pr; pr.x = (_Float16)c0; pr.y = (_Float16)c1;
            int off = lane * SA + (((iip >> 2) ^ (lane & 7)) << 3) + ((iip & 3) << 1);
            *(half2v*)&s_A2[off] = pr;
        }
    }
    __syncthreads();

    float f1A = 0.0f, f1B = 0.0f;
    f32x4 acc2[4];
    #pragma unroll
    for (int i = 0; i < 4; ++i) acc2[i] = (f32x4){0.f, 0.f, 0.f, 0.f};

    // ---- per-cell dual-a eval helpers ----
    auto do_full2 = [&](int ii, int jj, int row, _Float16* bp0, _Float16* bp1) {
        float k2  = s_gw[100 + ii].x;
        float cMw = cM0 * (s_gw[100 + ii].y * ((ii == 0) ? 1.0f : 2.0f));
        float2 gwv = s_gw[100 + jj];
        float cw  = cMw * ((jj == 0) ? 0.5f * gwv.y : gwv.y);
        // a0
        float sA   = k1sqA + k2 * k2;
        float rsA  = __builtin_amdgcn_rsqf(sA);
        float valA = phi_pair_pk(k1A, k1sqA, n2k1A, Ttk1A, L2, sA, sA * rsA,
                                 (k2 * rk1A) * k2 * (rsA * rsA * rsA), gwv.x) * cw;
        // a1
        float sB   = k1sqB + k2 * k2;
        float rsB  = __builtin_amdgcn_rsqf(sB);
        float valB = phi_pair_pk(k1B, k1sqB, n2k1B, Ttk1B, L2, sB, sB * rsB,
                                 (k2 * rk1B) * k2 * (rsB * rsB * rsB), gwv.x) * cw;
        f1A += valA; f1B += valB;
        int off = row * SP + (((jj >> 3) ^ (row & 7)) << 3) + (jj & 7);
        bp0[off] = (_Float16)valA;
        bp1[off] = (_Float16)valB;
    };
    auto do_cheap2 = [&](int ii, int jj, int row, _Float16* bp0, _Float16* bp1) {
        float k2  = s_gw[100 + ii].x;
        float cMw = cM0 * (s_gw[100 + ii].y * ((ii == 0) ? 1.0f : 2.0f));
        float2 gwv = s_gw[100 + jj];
        float cw  = cMw * ((jj == 0) ? 0.5f * gwv.y : gwv.y);
        float valA = phi_pair_cheap(k1sqA, L2, k1sqA + k2 * k2, gwv.x) * cw;
        float valB = phi_pair_cheap(k1sqB, L2, k1sqB + k2 * k2, gwv.x) * cw;
        f1A += valA; f1B += valB;
        int off = row * SP + (((jj >> 3) ^ (row & 7)) << 3) + (jj & 7);
        bp0[off] = (_Float16)valA;
        bp1[off] = (_Float16)valB;
    };

    _Float16* pA0 = s_phiT;                 // a0 buf0
    _Float16* pA1 = s_phiT + 32 * SP;       // a0 buf1
    _Float16* pB0 = s_phiT + 64 * SP;       // a1 buf0
    _Float16* pB1 = s_phiT + 96 * SP;       // a1 buf1

    // ======== produce chunk 0 (ii 0..31) into buf 0 of both a's ========
    {
        if (t < 32) {     // granule 11 (jj 88..95) zero
            half8 zz = {};
            int off = t * SP + ((11 ^ (t & 7)) << 3);
            *(half8*)&pA0[off] = zz;
            *(half8*)&pB0[off] = zz;
        }
        // full: ii 0..31 x jj 0..55 = 1792
        #pragma unroll
        for (int m = 0; m < 4; ++m) {
            int e = t + 512 * m;
            if (e < 1792) {
                int row = e / FT, jj = e - row * FT;
                do_full2(row, jj, row, pA0, pB0);
            }
        }
        // cheap: ii 0..31 x jj 56..87 = 1024 = 2/thread
        #pragma unroll
        for (int m = 0; m < 2; ++m) {
            int e = t + 512 * m;
            int row = e >> 5, jj = FT + (e & 31);
            do_cheap2(row, jj, row, pA0, pB0);
        }
    }
    __syncthreads();

    const int ia = w >> 2;         // wave's a-index
    const int zb = w & 3;          // wave's z-block
    const float* k1sel = ia ? &k1B : &k1A;   // (unused marker; keeps intent clear)

    for (int c = 0; c < 3; ++c) {
        const _Float16* rp = s_phiT + ia * (64 * SP) + (c & 1) * (32 * SP);

        // ---- stage 1 (MFMA, wave-local): TcT[ii 0..31][z-block zb], K=96 ----
        f32x4 acc1[2];
        acc1[0] = (f32x4){0.f,0.f,0.f,0.f};
        acc1[1] = (f32x4){0.f,0.f,0.f,0.f};
        {
            const int arow0 = n16;
            const int arow1 = 16 + n16;
            const int brow  = zb * 16 + n16;
            #pragma unroll
            for (int ks = 0; ks < 3; ++ks) {
                int kg = ks * 4 + quad;
                half8 af0 = *(const half8*)&rp[arow0 * SP + ((kg ^ (arow0 & 7)) << 3)];
                half8 af1 = *(const half8*)&rp[arow1 * SP + ((kg ^ (arow1 & 7)) << 3)];
                half8 bf  = *(const half8*)&s_B3T[brow * SP + ((kg ^ (brow & 7)) << 3)];
                acc1[0] = __builtin_amdgcn_mfma_f32_16x16x32_f16(af0, bf, acc1[0], 0, 0, 0);
                acc1[1] = __builtin_amdgcn_mfma_f32_16x16x32_f16(af1, bf, acc1[1], 0, 0, 0);
            }
        }

        // ---- in-wave C->B transpose: bf2[j] = TcT[ii=quad*8+j][z=zb*16+n16] ----
        half8 bf2;
        {
            half2v hA0; hA0.x = (_Float16)acc1[0].x; hA0.y = (_Float16)acc1[0].y;
            half2v hA1; hA1.x = (_Float16)acc1[0].z; hA1.y = (_Float16)acc1[0].w;
            half2v hB0; hB0.x = (_Float16)acc1[1].x; hB0.y = (_Float16)acc1[1].y;
            half2v hB1; hB1.x = (_Float16)acc1[1].z; hB1.y = (_Float16)acc1[1].w;
            int pkA0 = __builtin_bit_cast(int, hA0);
            int pkA1 = __builtin_bit_cast(int, hA1);
            int pkB0 = __builtin_bit_cast(int, hB0);
            int pkB1 = __builtin_bit_cast(int, hB1);
            const int addr_a = (((quad & 1) << 5) + n16) << 2;
            const int addr_b = addr_a + 64;
            int a0v = __builtin_amdgcn_ds_bpermute(addr_a, pkA0);
            int b0v = __builtin_amdgcn_ds_bpermute(addr_a, pkB0);
            int a1v = __builtin_amdgcn_ds_bpermute(addr_a, pkA1);
            int b1v = __builtin_amdgcn_ds_bpermute(addr_a, pkB1);
            int a2v = __builtin_amdgcn_ds_bpermute(addr_b, pkA0);
            int b2v = __builtin_amdgcn_ds_bpermute(addr_b, pkB0);
            int a3v = __builtin_amdgcn_ds_bpermute(addr_b, pkA1);
            int b3v = __builtin_amdgcn_ds_bpermute(addr_b, pkB1);
            const bool lo = (quad < 2);
            i32x4 wv;
            wv.x = lo ? a0v : b0v;
            wv.y = lo ? a1v : b1v;
            wv.z = lo ? a2v : b2v;
            wv.w = lo ? a3v : b3v;
            bf2 = __builtin_bit_cast(half8, wv);
        }

        // ---- stage 2 (MFMA): out[y-blocks][z-block zb] += A2 * bf2, K=32 ----
        {
            const int G = c * 4 + quad;
            #pragma unroll
            for (int yb = 0; yb < 4; ++yb) {
                int yrow = yb * 16 + n16;
                half8 a2f = *(const half8*)&s_A2[yrow * SA + ((G ^ (yrow & 7)) << 3)];
                acc2[yb] = __builtin_amdgcn_mfma_f32_16x16x32_f16(a2f, bf2, acc2[yb], 0, 0, 0);
            }
        }

        // ---- produce next chunk's phiT (other buffer, both a's) ----
        if (c == 0) {
            // chunk 1 (ii 32..63) into buf 1
            if (t < 32) {
                half8 zz = {};
                int off = t * SP + ((11 ^ (t & 7)) << 3);
                *(half8*)&pA1[off] = zz;
                *(half8*)&pB1[off] = zz;
            }
            // full: ii 32..55 x jj 0..55 = 1344
            #pragma unroll
            for (int m = 0; m < 3; ++m) {
                int e = t + 512 * m;
                if (e < 1344) {
                    int row = e / FT, jj = e - row * FT;
                    do_full2(32 + row, jj, row, pA1, pB1);
                }
            }
            // cheap: (ii 32..55 x jj 56..87 = 768) + (ii 56..63 x jj 0..87 = 704) = 1472
            #pragma unroll
            for (int m = 0; m < 3; ++m) {
                int e = t + 512 * m;
                if (e < 1472) {
                    int row, jj;
                    if (e < 768) { row = e >> 5; jj = FT + (e & 31); }
                    else { int e2 = e - 768; row = 24 + e2 / 88; jj = e2 - (row - 24) * 88; }
                    do_cheap2(32 + row, jj, row, pA1, pB1);
                }
            }
        } else if (c == 1) {
            // chunk 2 (ii 64..95) into buf 0: rows 0..23 cheap, rows 24..31 zero
            if (t < 120) {
                int row, slot;
                if (t < 96) { row = 24 + t / 12; int g = t - (row - 24) * 12; slot = g ^ (row & 7); }
                else        { row = t - 96;      slot = 11 ^ (row & 7); }
                half8 zz = {};
                *(half8*)&pA0[row * SP + (slot << 3)] = zz;
                *(half8*)&pB0[row * SP + (slot << 3)] = zz;
            }
            // cheap: ii 64..87 x jj 0..87 = 2112
            #pragma unroll
            for (int m = 0; m < 5; ++m) {
                int e = t + 512 * m;
                if (e < 2112) {
                    int row = e / 88, jj = e - row * 88;
                    do_cheap2(64 + row, jj, row, pA0, pB0);
                }
            }
        }
        __syncthreads();
    }

    // ---- F1 reductions -> 1/|F1| per a ----
    float vA = f1A, vB = f1B;
    #pragma unroll
    for (int off = 32; off > 0; off >>= 1) {
        vA += __shfl_down(vA, off, 64);
        vB += __shfl_down(vB, off, 64);
    }
    if (lane == 0) { s_redA[w] = vA; s_redB[w] = vB; }
    __syncthreads();
    if (t == 0) {
        float sA = 0.0f, sB = 0.0f;
        #pragma unroll
        for (int i = 0; i < 8; ++i) { sA += s_redA[i]; sB += s_redB[i]; }
        s_rden[0] = 1.0f / fabsf(sA);
        s_rden[1] = 1.0f / fabsf(sB);
    }
    __syncthreads();
    const float rden = s_rden[ia];

    // ---- epilogue: acc2[yb][r] = out[a0+ia][y = yb*16+quad*4+r][z = zb*16+n16] ----
    float* op = out + ((size_t)(a0 + ia) << 12) + (zb * 16 + n16);
    #pragma unroll
    for (int yb = 0; yb < 4; ++yb) {
        #pragma unroll
        for (int r = 0; r < 4; ++r) {
            int y = yb * 16 + quad * 4 + r;
            op[y * 64] = acc2[yb][r] * rden;
        }
    }
    (void)k1sel;
}

extern "C" void kernel_launch(void* const* d_in, const int* in_sizes, int n_in,
                              void* d_out, int out_size, void* d_ws, size_t ws_size,
                              hipStream_t stream) {
    const float* k1 = (const float*)d_in[0];
    const float* dy = (const float*)d_in[1];
    const float* dz = (const float*)d_in[2];
    const float* lL = (const float*)d_in[3];
    const float* lT = (const float*)d_in[4];
    const float* lM = (const float*)d_in[5];
    float* outp = (float*)d_out;
    hipLaunchKernelGGL(spectral_kernel, dim3(256), dim3(BLOCK), 0, stream,
                       k1, dy, dz, lL, lT, lM, outp);
}